// Round 8
// baseline (365.431 us; speedup 1.0000x reference)
//
#include <hip/hip_runtime.h>
#include <hip/hip_bf16.h>
#include <hip/hip_fp16.h>

#define HID 64
#define HEADS 4
#define GCNT 64
#define F_IN 16
#define NEG 0.2f
#define NBUCK 256
#define BSLOT 6144
#define SCHUNK 2048

typedef _Float16 f16x8 __attribute__((ext_vector_type(8)));
typedef float f32x4 __attribute__((ext_vector_type(4)));

__device__ __forceinline__ unsigned pack_h2(float a, float b) {
  __half2 h = __floats2half2_rn(a, b);
  union { __half2 h; unsigned u; } c;
  c.h = h;
  return c.u;
}
__device__ __forceinline__ __half2 uas_h2(unsigned u) {
  union { unsigned u; __half2 h; } c;
  c.u = u;
  return c.h;
}
__device__ __forceinline__ unsigned h2_as_u(__half2 h) {
  union { __half2 h; unsigned u; } c;
  c.h = h;
  return c.u;
}
__device__ __forceinline__ __half2 xor16_add(__half2 v) {
  unsigned u = (unsigned)__shfl_xor((int)h2_as_u(v), 16, 64);
  return __hadd2(v, uas_h2(u));
}

// ---------------- pre: zero bucket cursors + fold layer-0 attn through Win ----------------
__global__ __launch_bounds__(256) void k_pre(
    const float* __restrict__ W0, const float* __restrict__ asrc,
    const float* __restrict__ adst, const float* __restrict__ Win,
    const float* __restrict__ bin, int* __restrict__ bcur,
    float* __restrict__ vb, float* __restrict__ c8) {
  int t = threadIdx.x;
  if (blockIdx.x == 0) {
    bcur[t] = 0;
    return;
  }
  __shared__ float vaL[512];
#pragma unroll
  for (int it = 0; it < 2; ++it) {
    int idx = t + it * 256;
    int q = idx >> 6, j = idx & 63;
    const float* a = (q < 4) ? asrc : adst;
    int h = q & 3;
    float s = 0.f;
    for (int c = 0; c < 64; ++c) s += a[h * 64 + c] * W0[(h * 64 + c) * 64 + j];
    vaL[idx] = s;
  }
  __syncthreads();
  if (t < 128) {
    int q = t >> 4, k = t & 15;
    float s = 0.f;
    for (int j = 0; j < 64; ++j) s += vaL[q * 64 + j] * Win[j * F_IN + k];
    vb[t] = s;
  } else if (t < 136) {
    int q = t - 128;
    float s = 0.f;
    for (int j = 0; j < 64; ++j) s += vaL[q * 64 + j] * bin[j];
    c8[q] = s;
  }
}

// ---------------- fused: CSR pass 1 (bucket) + weight prep + inproj (independent work) ----------------
__global__ __launch_bounds__(256) void k_binit(
    const int* __restrict__ ei, int* __restrict__ bcur,
    unsigned* __restrict__ tmp, int E, int N,
    const float* __restrict__ x, const float* __restrict__ Win,
    const float* __restrict__ bin,
    const float* __restrict__ W0, const float* __restrict__ W1,
    const float* __restrict__ W2,
    __half* __restrict__ Wh3, __half* __restrict__ Wcat3,
    float* __restrict__ sums, const float* __restrict__ vb,
    const float* __restrict__ c8,
    float* __restrict__ as_, float* __restrict__ ad_,
    __half* __restrict__ hh, int BUK) {
  int t = threadIdx.x;
  if (blockIdx.x < BUK) {
    // ---- bucket path ----
    __shared__ int hist[NBUCK];
    __shared__ int base[NBUCK];
    int start = blockIdx.x * SCHUNK;
    int end = min(start + SCHUNK, E + N);
    hist[t] = 0;
    __syncthreads();
    unsigned val[8];
    int rank[8];
    bool ok[8];
#pragma unroll
    for (int k = 0; k < 8; ++k) {
      int i = start + t + k * 256;
      ok[k] = i < end;
      if (ok[k]) {
        int s, d;
        if (i < E) {
          s = ei[i];
          d = ei[E + i];
        } else {
          s = d = i - E;
        }
        val[k] = ((unsigned)d << 16) | (unsigned)s;
        rank[k] = atomicAdd(&hist[d >> 8], 1);
      }
    }
    __syncthreads();
    int h = hist[t];
    base[t] = h ? atomicAdd(&bcur[t], h) : 0;
    __syncthreads();
#pragma unroll
    for (int k = 0; k < 8; ++k) {
      if (ok[k]) {
        int bk = (int)(val[k] >> 24);
        int idx = base[bk] + rank[k];
        if (idx < BSLOT) tmp[(size_t)bk * BSLOT + idx] = val[k];
      }
    }
    return;
  }
  // ---- init path ----
  int b = blockIdx.x - BUK;
  if (b < 384) {
    int i = b * 256 + t;
    if (i < 49152) {
      const float* W = (i < 16384) ? W0 : (i < 32768) ? W1 : W2;
      Wh3[i] = __float2half(W[i & 16383]);
    } else {
      int j = i - 49152;
      int l = j >> 14;
      int r = j & 16383;
      int c = r >> 8;
      int k256 = r & 255;
      int h = k256 & 3, kk = k256 >> 2;
      const float* W = (l == 0) ? W0 : (l == 1) ? W1 : W2;
      Wcat3[j] = __float2half(0.25f * W[(h * 64 + c) * 64 + kk]);
    }
    return;
  }
  if (b < 401) {
    int i = (b - 384) * 256 + t;
    if (i < GCNT * HID + GCNT) sums[i] = 0.f;
    return;
  }
  int i = (b - 401) * 256 + t;
  if (i >= N * HID) return;
  int n = i >> 6, j = i & 63;
  const float* xr = x + (size_t)n * F_IN;
  const float* wr = Win + j * F_IN;
  float xv[F_IN];
  float acc = bin[j];
#pragma unroll
  for (int k = 0; k < F_IN; ++k) {
    xv[k] = xr[k];
    acc = fmaf(xv[k], wr[k], acc);
  }
  hh[i] = __float2half(acc);
  if (j < 8) {
    const float* vbq = vb + j * 16;
    float s = c8[j];
#pragma unroll
    for (int k = 0; k < F_IN; ++k) s = fmaf(xv[k], vbq[k], s);
    if (j < 4) as_[(size_t)n * 4 + j] = s;
    else ad_[(size_t)n * 4 + (j - 4)] = s;
  }
}

// ---------------- CSR pass 2: per-bucket counting sort -> rowptr + col ----------------
__global__ __launch_bounds__(256) void k_bsort(
    const unsigned* __restrict__ tmp, const int* __restrict__ bcur,
    int* __restrict__ rowptr, int* __restrict__ col, int N) {
  __shared__ int s[NBUCK];
  __shared__ int hist[NBUCK];
  __shared__ int pref[NBUCK];
  int b = blockIdx.x, t = threadIdx.x;
  int c = min(bcur[t], BSLOT);
  s[t] = c;
  __syncthreads();
  for (int o = 1; o < 256; o <<= 1) {
    int x = (t >= o) ? s[t - o] : 0;
    __syncthreads();
    s[t] += x;
    __syncthreads();
  }
  int base = (b == 0) ? 0 : s[b - 1];
  int total = s[255];
  int cntb = min(bcur[b], BSLOT);
  hist[t] = 0;
  __syncthreads();
  for (int j = t; j < cntb; j += 256)
    atomicAdd(&hist[(tmp[(size_t)b * BSLOT + j] >> 16) & 255], 1);
  __syncthreads();
  int v = hist[t];
  pref[t] = v;
  __syncthreads();
  for (int o = 1; o < 256; o <<= 1) {
    int x = (t >= o) ? pref[t - o] : 0;
    __syncthreads();
    pref[t] += x;
    __syncthreads();
  }
  pref[t] -= v;
  __syncthreads();
  int node = b * 256 + t;
  if (node < N) rowptr[node] = base + pref[t];
  if (b == 255 && t == 255) rowptr[N] = total;
  hist[t] = 0;
  __syncthreads();
  for (int j = t; j < cntb; j += 256) {
    unsigned e = tmp[(size_t)b * BSLOT + j];
    int d8 = (int)((e >> 16) & 255);
    int r = atomicAdd(&hist[d8], 1);
    col[base + pref[d8] + r] = (int)(e & 0xffffu);
  }
}

// ---------------- single-node helper (any deg): writes one M row (256 halves) to global ----------------
__device__ __forceinline__ void gat_one_node(
    int node, int lane, const __half* __restrict__ h, const float* __restrict__ as_,
    const float* __restrict__ ad_, const int* __restrict__ rowptr,
    const int* __restrict__ col, __half* __restrict__ Mrow) {
  int r0 = rowptr[node];
  int deg = rowptr[node + 1] - r0;
  float4 adv = *(const float4*)(ad_ + (size_t)node * 4);

  if (deg <= 64) {
    int off = 0;
    float x0 = 0.f, x1 = 0.f, x2 = 0.f, x3 = 0.f;
    if (lane < deg) {
      int s = col[r0 + lane];
      off = s << 6;
      float4 av = *(const float4*)(as_ + (size_t)s * 4);
      float e0 = av.x + adv.x; e0 = (e0 > 0.f) ? e0 : NEG * e0;
      float e1 = av.y + adv.y; e1 = (e1 > 0.f) ? e1 : NEG * e1;
      float e2 = av.z + adv.z; e2 = (e2 > 0.f) ? e2 : NEG * e2;
      float e3 = av.w + adv.w; e3 = (e3 > 0.f) ? e3 : NEG * e3;
      x0 = __expf(fminf(e0, 60.f));
      x1 = __expf(fminf(e1, 60.f));
      x2 = __expf(fminf(e2, 60.f));
      x3 = __expf(fminf(e3, 60.f));
    }
    float s0 = x0, s1 = x1, s2 = x2, s3 = x3;
#pragma unroll
    for (int o = 32; o; o >>= 1) {
      s0 += __shfl_xor(s0, o, 64);
      s1 += __shfl_xor(s1, o, 64);
      s2 += __shfl_xor(s2, o, 64);
      s3 += __shfl_xor(s3, o, 64);
    }
    unsigned w01 = pack_h2(x0 / (s0 + 1e-16f), x1 / (s1 + 1e-16f));
    unsigned w23 = pack_h2(x2 / (s2 + 1e-16f), x3 / (s3 + 1e-16f));
    __half2 acc01 = __floats2half2_rn(0.f, 0.f);
    __half2 acc23 = acc01;
#pragma unroll 4
    for (int j = 0; j < deg; ++j) {
      int oj = __builtin_amdgcn_readlane(off, j) + lane;
      unsigned W01 = __builtin_amdgcn_readlane(w01, j);
      unsigned W23 = __builtin_amdgcn_readlane(w23, j);
      __half2 hv = __half2half2(h[oj]);
      acc01 = __hfma2(hv, uas_h2(W01), acc01);
      acc23 = __hfma2(hv, uas_h2(W23), acc23);
    }
    *(__half2*)&Mrow[lane * 4] = acc01;
    *(__half2*)&Mrow[lane * 4 + 2] = acc23;
    return;
  }
  float m0 = -1e30f, m1 = -1e30f, m2 = -1e30f, m3 = -1e30f;
  for (int j = lane; j < deg; j += 64) {
    int s = col[r0 + j];
    float4 av = *(const float4*)(as_ + (size_t)s * 4);
    float e0 = av.x + adv.x; e0 = (e0 > 0.f) ? e0 : NEG * e0; m0 = fmaxf(m0, e0);
    float e1 = av.y + adv.y; e1 = (e1 > 0.f) ? e1 : NEG * e1; m1 = fmaxf(m1, e1);
    float e2 = av.z + adv.z; e2 = (e2 > 0.f) ? e2 : NEG * e2; m2 = fmaxf(m2, e2);
    float e3 = av.w + adv.w; e3 = (e3 > 0.f) ? e3 : NEG * e3; m3 = fmaxf(m3, e3);
  }
#pragma unroll
  for (int o = 32; o; o >>= 1) {
    m0 = fmaxf(m0, __shfl_xor(m0, o, 64));
    m1 = fmaxf(m1, __shfl_xor(m1, o, 64));
    m2 = fmaxf(m2, __shfl_xor(m2, o, 64));
    m3 = fmaxf(m3, __shfl_xor(m3, o, 64));
  }
  float s0 = 0.f, s1 = 0.f, s2 = 0.f, s3 = 0.f;
  for (int j = lane; j < deg; j += 64) {
    int s = col[r0 + j];
    float4 av = *(const float4*)(as_ + (size_t)s * 4);
    float e0 = av.x + adv.x; e0 = (e0 > 0.f) ? e0 : NEG * e0; s0 += __expf(e0 - m0);
    float e1 = av.y + adv.y; e1 = (e1 > 0.f) ? e1 : NEG * e1; s1 += __expf(e1 - m1);
    float e2 = av.z + adv.z; e2 = (e2 > 0.f) ? e2 : NEG * e2; s2 += __expf(e2 - m2);
    float e3 = av.w + adv.w; e3 = (e3 > 0.f) ? e3 : NEG * e3; s3 += __expf(e3 - m3);
  }
#pragma unroll
  for (int o = 32; o; o >>= 1) {
    s0 += __shfl_xor(s0, o, 64);
    s1 += __shfl_xor(s1, o, 64);
    s2 += __shfl_xor(s2, o, 64);
    s3 += __shfl_xor(s3, o, 64);
  }
  float i0 = 1.f / (s0 + 1e-16f), i1 = 1.f / (s1 + 1e-16f);
  float i2 = 1.f / (s2 + 1e-16f), i3 = 1.f / (s3 + 1e-16f);
  float a0 = 0.f, a1 = 0.f, a2 = 0.f, a3 = 0.f;
  for (int j = 0; j < deg; ++j) {
    int s = col[r0 + j];
    float4 av = *(const float4*)(as_ + (size_t)s * 4);
    float e0 = av.x + adv.x; e0 = (e0 > 0.f) ? e0 : NEG * e0;
    float e1 = av.y + adv.y; e1 = (e1 > 0.f) ? e1 : NEG * e1;
    float e2 = av.z + adv.z; e2 = (e2 > 0.f) ? e2 : NEG * e2;
    float e3 = av.w + adv.w; e3 = (e3 > 0.f) ? e3 : NEG * e3;
    float hv = __half2float(h[(s << 6) + lane]);
    a0 = fmaf(__expf(e0 - m0) * i0, hv, a0);
    a1 = fmaf(__expf(e1 - m1) * i1, hv, a1);
    a2 = fmaf(__expf(e2 - m2) * i2, hv, a2);
    a3 = fmaf(__expf(e3 - m3) * i3, hv, a3);
  }
  *(__half2*)&Mrow[lane * 4] = __floats2half2_rn(a0, a1);
  *(__half2*)&Mrow[lane * 4 + 2] = __floats2half2_rn(a2, a3);
}

// ---------------- one pair (serial path; handles slow cases); writes global M rows ----------------
__device__ __forceinline__ void gat_pair(
    int pr, int lane, int half, int l5, int N,
    const __half* __restrict__ h, const float* __restrict__ as_,
    const float* __restrict__ ad_, const int* __restrict__ rowptr,
    const int* __restrict__ col, __half* __restrict__ M) {
  int n0 = pr * 2;
  int n1 = min(n0 + 1, N - 1);
  int mynode = half ? n1 : n0;
  int r0 = rowptr[mynode];
  int dg = rowptr[mynode + 1] - r0;
  int dgA = __builtin_amdgcn_readlane(dg, 0);
  int dgB = __builtin_amdgcn_readlane(dg, 32);

  if (dgA <= 32 && dgB <= 32) {
    float4 adv = *(const float4*)(ad_ + (size_t)mynode * 4);
    int off = 0;
    float x0 = 0.f, x1 = 0.f, x2 = 0.f, x3 = 0.f;
    if (l5 < dg) {
      int s = col[r0 + l5];
      off = s << 6;
      float4 av = *(const float4*)(as_ + (size_t)s * 4);
      float e0 = av.x + adv.x; e0 = (e0 > 0.f) ? e0 : NEG * e0;
      float e1 = av.y + adv.y; e1 = (e1 > 0.f) ? e1 : NEG * e1;
      float e2 = av.z + adv.z; e2 = (e2 > 0.f) ? e2 : NEG * e2;
      float e3 = av.w + adv.w; e3 = (e3 > 0.f) ? e3 : NEG * e3;
      x0 = __expf(fminf(e0, 60.f));
      x1 = __expf(fminf(e1, 60.f));
      x2 = __expf(fminf(e2, 60.f));
      x3 = __expf(fminf(e3, 60.f));
    }
    float s0 = x0, s1 = x1, s2 = x2, s3 = x3;
#pragma unroll
    for (int o = 16; o; o >>= 1) {
      s0 += __shfl_xor(s0, o, 64);
      s1 += __shfl_xor(s1, o, 64);
      s2 += __shfl_xor(s2, o, 64);
      s3 += __shfl_xor(s3, o, 64);
    }
    unsigned w01 = pack_h2(x0 / (s0 + 1e-16f), x1 / (s1 + 1e-16f));
    unsigned w23 = pack_h2(x2 / (s2 + 1e-16f), x3 / (s3 + 1e-16f));

    int g = l5 >> 4, li = l5 & 15;
    const uint2* h4p = (const uint2*)h;
    __half2 z = __floats2half2_rn(0.f, 0.f);
    __half2 a0_01 = z, a0_23 = z, a1_01 = z, a1_23 = z;
    __half2 a2_01 = z, a2_23 = z, a3_01 = z, a3_23 = z;
    int mdeg = max(dgA, dgB);
    int baddr = half << 7;
#pragma unroll 2
    for (int j = 0; j < mdeg; j += 2) {
      int addr = baddr + (j + g) * 4;
      int oj = __builtin_amdgcn_ds_bpermute(addr, off);
      unsigned W01 = (unsigned)__builtin_amdgcn_ds_bpermute(addr, (int)w01);
      unsigned W23 = (unsigned)__builtin_amdgcn_ds_bpermute(addr, (int)w23);
      uint2 hv = h4p[(oj >> 2) + li];
      __half2 ha = uas_h2(hv.x), hb = uas_h2(hv.y);
      __half2 wA = uas_h2(W01), wB = uas_h2(W23);
      __half2 c0 = __low2half2(ha), c1 = __high2half2(ha);
      __half2 c2 = __low2half2(hb), c3 = __high2half2(hb);
      a0_01 = __hfma2(c0, wA, a0_01); a0_23 = __hfma2(c0, wB, a0_23);
      a1_01 = __hfma2(c1, wA, a1_01); a1_23 = __hfma2(c1, wB, a1_23);
      a2_01 = __hfma2(c2, wA, a2_01); a2_23 = __hfma2(c2, wB, a2_23);
      a3_01 = __hfma2(c3, wA, a3_01); a3_23 = __hfma2(c3, wB, a3_23);
    }
    a0_01 = xor16_add(a0_01); a0_23 = xor16_add(a0_23);
    a1_01 = xor16_add(a1_01); a1_23 = xor16_add(a1_23);
    a2_01 = xor16_add(a2_01); a2_23 = xor16_add(a2_23);
    a3_01 = xor16_add(a3_01); a3_23 = xor16_add(a3_23);
    if (g == 0) {
      __half* row = M + (size_t)mynode * 256 + li * 16;
      uint4 st1, st2;
      st1.x = h2_as_u(a0_01); st1.y = h2_as_u(a0_23);
      st1.z = h2_as_u(a1_01); st1.w = h2_as_u(a1_23);
      st2.x = h2_as_u(a2_01); st2.y = h2_as_u(a2_23);
      st2.z = h2_as_u(a3_01); st2.w = h2_as_u(a3_23);
      *(uint4*)&row[0] = st1;
      *(uint4*)&row[8] = st2;
    }
  } else {
    gat_one_node(n0, lane, h, as_, ad_, rowptr, col, M + (size_t)n0 * 256);
    if (n1 != n0) gat_one_node(n1, lane, h, as_, ad_, rowptr, col, M + (size_t)n1 * 256);
  }
}

// ---------------- phase 1 only: gather + softmax-weighted aggregate -> global M ----------------
// (diagnostic split: per-dispatch timing attributes the 61us between phases)
__global__ __launch_bounds__(256) void k_gather(
    const __half* __restrict__ h, const float* __restrict__ as_,
    const float* __restrict__ ad_, const int* __restrict__ rowptr,
    const int* __restrict__ col, __half* __restrict__ M, int N) {
  __shared__ uint4 EBs[4][128];
  int tid = threadIdx.x;
  int lane = tid & 63, wv = tid >> 6;
  int tile = blockIdx.x;
  int half = lane >> 5, l5 = lane & 31;
  int npairs = (N + 1) >> 1;

  int pr0 = tile * 8 + wv * 2;
  int pr1 = pr0 + 1;
  bool has0 = pr0 < npairs, has1 = pr1 < npairs;
  if (has0 && has1) {
    int my0 = min(pr0 * 2 + half, N - 1);
    int my1 = min(pr1 * 2 + half, N - 1);
    int r0a = rowptr[my0];
    int dga = rowptr[my0 + 1] - r0a;
    int r0b = rowptr[my1];
    int dgb = rowptr[my1 + 1] - r0b;
    int dA0 = __builtin_amdgcn_readlane(dga, 0);
    int dB0 = __builtin_amdgcn_readlane(dga, 32);
    int dA1 = __builtin_amdgcn_readlane(dgb, 0);
    int dB1 = __builtin_amdgcn_readlane(dgb, 32);

    if (dA0 <= 32 && dB0 <= 32 && dA1 <= 32 && dB1 <= 32) {
      float4 adva = *(const float4*)(ad_ + (size_t)my0 * 4);
      float4 advb = *(const float4*)(ad_ + (size_t)my1 * 4);
      int offa = 0, offb = 0;
      float xa0 = 0.f, xa1 = 0.f, xa2 = 0.f, xa3 = 0.f;
      float xb0 = 0.f, xb1 = 0.f, xb2 = 0.f, xb3 = 0.f;
      if (l5 < dga) {
        int s = col[r0a + l5];
        offa = s << 6;
        float4 av = *(const float4*)(as_ + (size_t)s * 4);
        float e0 = av.x + adva.x; e0 = (e0 > 0.f) ? e0 : NEG * e0;
        float e1 = av.y + adva.y; e1 = (e1 > 0.f) ? e1 : NEG * e1;
        float e2 = av.z + adva.z; e2 = (e2 > 0.f) ? e2 : NEG * e2;
        float e3 = av.w + adva.w; e3 = (e3 > 0.f) ? e3 : NEG * e3;
        xa0 = __expf(fminf(e0, 60.f));
        xa1 = __expf(fminf(e1, 60.f));
        xa2 = __expf(fminf(e2, 60.f));
        xa3 = __expf(fminf(e3, 60.f));
      }
      if (l5 < dgb) {
        int s = col[r0b + l5];
        offb = s << 6;
        float4 av = *(const float4*)(as_ + (size_t)s * 4);
        float e0 = av.x + advb.x; e0 = (e0 > 0.f) ? e0 : NEG * e0;
        float e1 = av.y + advb.y; e1 = (e1 > 0.f) ? e1 : NEG * e1;
        float e2 = av.z + advb.z; e2 = (e2 > 0.f) ? e2 : NEG * e2;
        float e3 = av.w + advb.w; e3 = (e3 > 0.f) ? e3 : NEG * e3;
        xb0 = __expf(fminf(e0, 60.f));
        xb1 = __expf(fminf(e1, 60.f));
        xb2 = __expf(fminf(e2, 60.f));
        xb3 = __expf(fminf(e3, 60.f));
      }
      float sa0 = xa0, sa1 = xa1, sa2 = xa2, sa3 = xa3;
      float sb0 = xb0, sb1 = xb1, sb2 = xb2, sb3 = xb3;
#pragma unroll
      for (int o = 16; o; o >>= 1) {
        sa0 += __shfl_xor(sa0, o, 64);
        sa1 += __shfl_xor(sa1, o, 64);
        sa2 += __shfl_xor(sa2, o, 64);
        sa3 += __shfl_xor(sa3, o, 64);
        sb0 += __shfl_xor(sb0, o, 64);
        sb1 += __shfl_xor(sb1, o, 64);
        sb2 += __shfl_xor(sb2, o, 64);
        sb3 += __shfl_xor(sb3, o, 64);
      }
      unsigned w01a = pack_h2(xa0 / (sa0 + 1e-16f), xa1 / (sa1 + 1e-16f));
      unsigned w23a = pack_h2(xa2 / (sa2 + 1e-16f), xa3 / (sa3 + 1e-16f));
      unsigned w01b = pack_h2(xb0 / (sb0 + 1e-16f), xb1 / (sb1 + 1e-16f));
      unsigned w23b = pack_h2(xb2 / (sb2 + 1e-16f), xb3 / (sb3 + 1e-16f));

      uint4* EB = EBs[wv];
      EB[half * 32 + l5] = make_uint4((unsigned)offa, w01a, w23a, 0u);
      EB[64 + half * 32 + l5] = make_uint4((unsigned)offb, w01b, w23b, 0u);

      int mm = max(max(dA0, dB0), max(dA1, dB1));
      int eA = half * 32;
      int eB = 64 + eA;

      int g = l5 >> 4, li = l5 & 15;
      const uint2* h4p = (const uint2*)h;
      __half2 z = __floats2half2_rn(0.f, 0.f);
      __half2 pa0 = z, pa1 = z, pa2 = z, pa3 = z, pa4 = z, pa5 = z, pa6 = z, pa7 = z;
      __half2 pb0 = z, pb1 = z, pb2 = z, pb3 = z, pb4 = z, pb5 = z, pb6 = z, pb7 = z;
#pragma unroll 2
      for (int j = 0; j < mm; j += 2) {
        uint4 ra = EB[eA + j + g];
        uint4 rb = EB[eB + j + g];
        uint2 hva = h4p[((int)ra.x >> 2) + li];
        uint2 hvb = h4p[((int)rb.x >> 2) + li];
        {
          __half2 ha = uas_h2(hva.x), hb = uas_h2(hva.y);
          __half2 wA = uas_h2(ra.y), wB = uas_h2(ra.z);
          __half2 c0 = __low2half2(ha), c1 = __high2half2(ha);
          __half2 c2 = __low2half2(hb), c3 = __high2half2(hb);
          pa0 = __hfma2(c0, wA, pa0); pa1 = __hfma2(c0, wB, pa1);
          pa2 = __hfma2(c1, wA, pa2); pa3 = __hfma2(c1, wB, pa3);
          pa4 = __hfma2(c2, wA, pa4); pa5 = __hfma2(c2, wB, pa5);
          pa6 = __hfma2(c3, wA, pa6); pa7 = __hfma2(c3, wB, pa7);
        }
        {
          __half2 ha = uas_h2(hvb.x), hb = uas_h2(hvb.y);
          __half2 wA = uas_h2(rb.y), wB = uas_h2(rb.z);
          __half2 c0 = __low2half2(ha), c1 = __high2half2(ha);
          __half2 c2 = __low2half2(hb), c3 = __high2half2(hb);
          pb0 = __hfma2(c0, wA, pb0); pb1 = __hfma2(c0, wB, pb1);
          pb2 = __hfma2(c1, wA, pb2); pb3 = __hfma2(c1, wB, pb3);
          pb4 = __hfma2(c2, wA, pb4); pb5 = __hfma2(c2, wB, pb5);
          pb6 = __hfma2(c3, wA, pb6); pb7 = __hfma2(c3, wB, pb7);
        }
      }
      pa0 = xor16_add(pa0); pa1 = xor16_add(pa1); pa2 = xor16_add(pa2); pa3 = xor16_add(pa3);
      pa4 = xor16_add(pa4); pa5 = xor16_add(pa5); pa6 = xor16_add(pa6); pa7 = xor16_add(pa7);
      pb0 = xor16_add(pb0); pb1 = xor16_add(pb1); pb2 = xor16_add(pb2); pb3 = xor16_add(pb3);
      pb4 = xor16_add(pb4); pb5 = xor16_add(pb5); pb6 = xor16_add(pb6); pb7 = xor16_add(pb7);
      if (g == 0) {
        __half* rowA = M + (size_t)my0 * 256 + li * 16;
        __half* rowB = M + (size_t)my1 * 256 + li * 16;
        uint4 s1, s2;
        s1.x = h2_as_u(pa0); s1.y = h2_as_u(pa1); s1.z = h2_as_u(pa2); s1.w = h2_as_u(pa3);
        s2.x = h2_as_u(pa4); s2.y = h2_as_u(pa5); s2.z = h2_as_u(pa6); s2.w = h2_as_u(pa7);
        *(uint4*)&rowA[0] = s1;
        *(uint4*)&rowA[8] = s2;
        s1.x = h2_as_u(pb0); s1.y = h2_as_u(pb1); s1.z = h2_as_u(pb2); s1.w = h2_as_u(pb3);
        s2.x = h2_as_u(pb4); s2.y = h2_as_u(pb5); s2.z = h2_as_u(pb6); s2.w = h2_as_u(pb7);
        *(uint4*)&rowB[0] = s1;
        *(uint4*)&rowB[8] = s2;
      }
    } else {
      gat_pair(pr0, lane, half, l5, N, h, as_, ad_, rowptr, col, M);
      gat_pair(pr1, lane, half, l5, N, h, as_, ad_, rowptr, col, M);
    }
  } else if (has0) {
    gat_pair(pr0, lane, half, l5, N, h, as_, ad_, rowptr, col, M);
  }
}

// ---------------- phase 2 only: head-mean GEMM from global M (+ next attn / pool) ----------------
template <bool FIN>
__global__ __launch_bounds__(256) void k_gemm(
    const __half* __restrict__ M, const __half* __restrict__ Wcat,
    const float* __restrict__ bg, const __half* __restrict__ Wn,
    const float* __restrict__ asrc, const float* __restrict__ adst,
    __half* __restrict__ hout, float* __restrict__ nas, float* __restrict__ nad,
    const int* __restrict__ batchv, float* __restrict__ gsums, int N) {
  __shared__ __half O[16 * 72];
  int tid = threadIdx.x;
  int lane = tid & 63, wv = tid >> 6;
  int tile = blockIdx.x;
  int quad = lane >> 4, n16 = lane & 15;
  const f16x8* WC = (const f16x8*)Wcat;
  int ch1 = wv * 16 + n16;
  float bias1 = bg[ch1];
  f32x4 c1 = {0.f, 0.f, 0.f, 0.f};
  const __half* Mrow = M + (size_t)(tile * 16 + n16) * 256;
#pragma unroll
  for (int i = 0; i < 8; ++i) {
    f16x8 a = *(const f16x8*)&Mrow[(i * 4 + quad) * 8];
    c1 = __builtin_amdgcn_mfma_f32_16x16x32_f16(a, WC[ch1 * 32 + i * 4 + quad], c1, 0, 0, 0);
  }
#pragma unroll
  for (int r = 0; r < 4; ++r) {
    float v = fmaxf(c1[r] + bias1, 0.f);
    O[(quad * 4 + r) * 72 + ch1] = __float2half(v);
  }
  __syncthreads();

  if (FIN) {
    // LDS-staged mean pool: 64 threads, one channel each
    if (tid < 64) {
      float* cnt_ = gsums + GCNT * HID;
      int c = tid;
      int nmax = min(16, N - tile * 16);
      int curg = -1;
      float acc = 0.f;
      int cacc = 0;
      for (int i = 0; i < nmax; ++i) {
        int gph = batchv[tile * 16 + i];
        float v = __half2float(O[i * 72 + c]);
        if (gph != curg) {
          if (curg >= 0) {
            atomicAdd(&gsums[curg * HID + c], acc);
            if (c == 0) atomicAdd(&cnt_[curg], (float)cacc);
          }
          curg = gph;
          acc = 0.f;
          cacc = 0;
        }
        acc += v;
        ++cacc;
      }
      if (curg >= 0) {
        atomicAdd(&gsums[curg * HID + c], acc);
        if (c == 0) atomicAdd(&cnt_[curg], (float)cacc);
      }
    }
    return;
  }

  {
    int nd = tid >> 4, c0 = (tid & 15) * 4;
    int node = tile * 16 + nd;
    if (node < N) {
      uint2 v = *(const uint2*)&O[nd * 72 + c0];
      *(uint2*)&hout[(size_t)node * 64 + c0] = v;
    }
  }
  {
    const f16x8* WN = (const f16x8*)Wn;
    f16x8 a0 = *(const f16x8*)&O[n16 * 72 + quad * 8];
    f16x8 a1 = *(const f16x8*)&O[n16 * 72 + 32 + quad * 8];
    f32x4 accs[4];
#pragma unroll
    for (int nt = 0; nt < 4; ++nt) {
      int ch = wv * 64 + nt * 16 + n16;
      f32x4 zz = {0.f, 0.f, 0.f, 0.f};
      zz = __builtin_amdgcn_mfma_f32_16x16x32_f16(a0, WN[ch * 8 + quad], zz, 0, 0, 0);
      zz = __builtin_amdgcn_mfma_f32_16x16x32_f16(a1, WN[ch * 8 + 4 + quad], zz, 0, 0, 0);
      accs[nt] = zz;
    }
#pragma unroll
    for (int r = 0; r < 4; ++r) {
      float vs = 0.f, vd = 0.f;
#pragma unroll
      for (int nt = 0; nt < 4; ++nt) {
        int ch = wv * 64 + nt * 16 + n16;
        vs = fmaf(accs[nt][r], asrc[ch], vs);
        vd = fmaf(accs[nt][r], adst[ch], vd);
      }
#pragma unroll
      for (int o = 8; o; o >>= 1) {
        vs += __shfl_xor(vs, o, 64);
        vd += __shfl_xor(vd, o, 64);
      }
      int node = tile * 16 + quad * 4 + r;
      if (n16 == 0 && node < N) {
        nas[(size_t)node * 4 + wv] = vs;
        nad[(size_t)node * 4 + wv] = vd;
      }
    }
  }
}

// ---------------- readout ----------------
__global__ void k_out(const float* __restrict__ sums, const float* __restrict__ cnt,
                      const float* __restrict__ Wout, const float* __restrict__ bout,
                      float* __restrict__ out) {
  int g = blockIdx.x, lane = threadIdx.x;
  float cg = fmaxf(cnt[g], 1.f);
  float v = (sums[g * HID + lane] / cg) * Wout[lane];
#pragma unroll
  for (int o = 32; o; o >>= 1) v += __shfl_xor(v, o, 64);
  if (lane == 0) out[g] = 1.f / (1.f + __expf(-v));
}

extern "C" void kernel_launch(void* const* d_in, const int* in_sizes, int n_in,
                              void* d_out, int out_size, void* d_ws, size_t ws_size,
                              hipStream_t stream) {
  const float* x    = (const float*)d_in[0];
  const int*   ei   = (const int*)d_in[1];
  const int*   batch= (const int*)d_in[2];
  const float* Win  = (const float*)d_in[3];
  const float* bin  = (const float*)d_in[4];
  const float* Wout = (const float*)d_in[5];
  const float* bout = (const float*)d_in[6];
  const float* Wl[3]    = {(const float*)d_in[7],  (const float*)d_in[11], (const float*)d_in[15]};
  const float* asrcl[3] = {(const float*)d_in[8],  (const float*)d_in[12], (const float*)d_in[16]};
  const float* adstl[3] = {(const float*)d_in[9],  (const float*)d_in[13], (const float*)d_in[17]};
  const float* bgl[3]   = {(const float*)d_in[10], (const float*)d_in[14], (const float*)d_in[18]};

  int N = in_sizes[2];       // 50000
  int E = in_sizes[1] / 2;   // 800000
  int EE = E + N;
  int tiles = (N + 15) / 16;

  char* p = (char*)d_ws;
  auto alloc = [&](size_t bytes) {
    char* r = p;
    p += (bytes + 255) & ~(size_t)255;
    return r;
  };
  size_t msz = (size_t)tiles * 16 * 256 * 2;           // 25.6 MB (M scratch)
  size_t tsz = (size_t)NBUCK * BSLOT * 4;              // 6.3 MB (bucket tmp)
  char*  ov  = alloc(msz > tsz ? msz : tsz);           // overlay: tmp dead before first k_gather
  unsigned* tmp = (unsigned*)ov;
  __half*   M   = (__half*)ov;
  int*      rowptr = (int*)alloc((size_t)(N + 1) * 4);
  int*      col    = (int*)alloc((size_t)EE * 4);
  int*      bcur   = (int*)alloc(NBUCK * 4);
  float*    vb     = (float*)alloc(128 * 4);
  float*    c8     = (float*)alloc(8 * 4);
  __half*   hhA    = (__half*)alloc((size_t)N * HID * 2);
  __half*   hhB    = (__half*)alloc((size_t)N * HID * 2);
  float*    asA    = (float*)alloc((size_t)N * HEADS * 4);
  float*    adA    = (float*)alloc((size_t)N * HEADS * 4);
  float*    asB    = (float*)alloc((size_t)N * HEADS * 4);
  float*    adB    = (float*)alloc((size_t)N * HEADS * 4);
  __half*   Wh3    = (__half*)alloc(3 * 16384 * 2);
  __half*   Wcat3  = (__half*)alloc(3 * 16384 * 2);
  float*    sums   = (float*)alloc((size_t)(GCNT * HID + GCNT) * 4);
  float*    cnt    = sums + GCNT * HID;

  int BUK = (EE + SCHUNK - 1) / SCHUNK;
  int initB = 401 + (N * HID + 255) / 256;

  k_pre<<<2, 256, 0, stream>>>(Wl[0], asrcl[0], adstl[0], Win, bin, bcur, vb, c8);

  k_binit<<<BUK + initB, 256, 0, stream>>>(ei, bcur, tmp, E, N,
                                           x, Win, bin, Wl[0], Wl[1], Wl[2],
                                           Wh3, Wcat3, sums, vb, c8, asA, adA, hhA, BUK);

  k_bsort<<<NBUCK, 256, 0, stream>>>(tmp, bcur, rowptr, col, N);

  // layer 0
  k_gather<<<tiles, 256, 0, stream>>>(hhA, asA, adA, rowptr, col, M, N);
  k_gemm<false><<<tiles, 256, 0, stream>>>(M, Wcat3, bgl[0], Wh3 + 16384, asrcl[1], adstl[1],
                                           hhB, asB, adB, nullptr, nullptr, N);
  // layer 1
  k_gather<<<tiles, 256, 0, stream>>>(hhB, asB, adB, rowptr, col, M, N);
  k_gemm<false><<<tiles, 256, 0, stream>>>(M, Wcat3 + 16384, bgl[1], Wh3 + 32768, asrcl[2], adstl[2],
                                           hhA, asA, adA, nullptr, nullptr, N);
  // layer 2 (final: fused pool)
  k_gather<<<tiles, 256, 0, stream>>>(hhA, asA, adA, rowptr, col, M, N);
  k_gemm<true><<<tiles, 256, 0, stream>>>(M, Wcat3 + 32768, bgl[2], nullptr, nullptr, nullptr,
                                          nullptr, nullptr, nullptr, batch, sums, N);

  k_out<<<GCNT, 64, 0, stream>>>(sums, cnt, Wout, bout, (float*)d_out);
}

// Round 9
// 295.718 us; speedup vs baseline: 1.2357x; 1.2357x over previous
//
#include <hip/hip_runtime.h>
#include <hip/hip_bf16.h>
#include <hip/hip_fp16.h>

#define HID 64
#define HEADS 4
#define GCNT 64
#define F_IN 16
#define NEG 0.2f
#define NBUCK 256
#define BSLOT 6144
#define SCHUNK 2048
#define BSTRIDE 16  // bcur counters padded to one per 64B line (atomic-line serialization fix)

typedef _Float16 f16x8 __attribute__((ext_vector_type(8)));
typedef float f32x4 __attribute__((ext_vector_type(4)));

__device__ __forceinline__ unsigned pack_h2(float a, float b) {
  __half2 h = __floats2half2_rn(a, b);
  union { __half2 h; unsigned u; } c;
  c.h = h;
  return c.u;
}
__device__ __forceinline__ __half2 uas_h2(unsigned u) {
  union { unsigned u; __half2 h; } c;
  c.u = u;
  return c.h;
}
__device__ __forceinline__ unsigned h2_as_u(__half2 h) {
  union { __half2 h; unsigned u; } c;
  c.h = h;
  return c.u;
}
__device__ __forceinline__ __half2 xor16_add(__half2 v) {
  unsigned u = (unsigned)__shfl_xor((int)h2_as_u(v), 16, 64);
  return __hadd2(v, uas_h2(u));
}

// ---------------- pre: zero padded bucket cursors + fold layer-0 attn through Win ----------------
__global__ __launch_bounds__(256) void k_pre(
    const float* __restrict__ W0, const float* __restrict__ asrc,
    const float* __restrict__ adst, const float* __restrict__ Win,
    const float* __restrict__ bin, int* __restrict__ bcur,
    float* __restrict__ vb, float* __restrict__ c8) {
  int t = threadIdx.x;
  if (blockIdx.x == 0) {
    for (int i = t; i < NBUCK * BSTRIDE; i += 256) bcur[i] = 0;
    return;
  }
  __shared__ float vaL[512];
#pragma unroll
  for (int it = 0; it < 2; ++it) {
    int idx = t + it * 256;
    int q = idx >> 6, j = idx & 63;
    const float* a = (q < 4) ? asrc : adst;
    int h = q & 3;
    float s = 0.f;
    for (int c = 0; c < 64; ++c) s += a[h * 64 + c] * W0[(h * 64 + c) * 64 + j];
    vaL[idx] = s;
  }
  __syncthreads();
  if (t < 128) {
    int q = t >> 4, k = t & 15;
    float s = 0.f;
    for (int j = 0; j < 64; ++j) s += vaL[q * 64 + j] * Win[j * F_IN + k];
    vb[t] = s;
  } else if (t < 136) {
    int q = t - 128;
    float s = 0.f;
    for (int j = 0; j < 64; ++j) s += vaL[q * 64 + j] * bin[j];
    c8[q] = s;
  }
}

// ---------------- fused: CSR pass 1 (bucket) + weight prep + LDS-staged inproj ----------------
__global__ __launch_bounds__(256) void k_binit(
    const int* __restrict__ ei, int* __restrict__ bcur,
    unsigned* __restrict__ tmp, int E, int N,
    const float* __restrict__ x, const float* __restrict__ Win,
    const float* __restrict__ bin,
    const float* __restrict__ W0, const float* __restrict__ W1,
    const float* __restrict__ W2,
    __half* __restrict__ Wh3, __half* __restrict__ Wcat3,
    float* __restrict__ sums, const float* __restrict__ vb,
    const float* __restrict__ c8,
    float* __restrict__ as_, float* __restrict__ ad_,
    __half* __restrict__ hh, int BUK) {
  int t = threadIdx.x;
  if (blockIdx.x < BUK) {
    // ---- bucket path ----
    __shared__ int hist[NBUCK];
    __shared__ int base[NBUCK];
    int start = blockIdx.x * SCHUNK;
    int end = min(start + SCHUNK, E + N);
    hist[t] = 0;
    __syncthreads();
    unsigned val[8];
    int rank[8];
    bool ok[8];
#pragma unroll
    for (int k = 0; k < 8; ++k) {
      int i = start + t + k * 256;
      ok[k] = i < end;
      if (ok[k]) {
        int s, d;
        if (i < E) {
          s = ei[i];
          d = ei[E + i];
        } else {
          s = d = i - E;
        }
        val[k] = ((unsigned)d << 16) | (unsigned)s;
        rank[k] = atomicAdd(&hist[d >> 8], 1);
      }
    }
    __syncthreads();
    int h = hist[t];
    // padded counters: one atomic per 64B line -> no same-line serialization
    base[t] = h ? atomicAdd(&bcur[t * BSTRIDE], h) : 0;
    __syncthreads();
#pragma unroll
    for (int k = 0; k < 8; ++k) {
      if (ok[k]) {
        int bk = (int)(val[k] >> 24);
        int idx = base[bk] + rank[k];
        if (idx < BSLOT) tmp[(size_t)bk * BSLOT + idx] = val[k];
      }
    }
    return;
  }
  // ---- weight prep / zero path ----
  int b = blockIdx.x - BUK;
  if (b < 384) {
    int i = b * 256 + t;
    if (i < 49152) {
      const float* W = (i < 16384) ? W0 : (i < 32768) ? W1 : W2;
      Wh3[i] = __float2half(W[i & 16383]);
    } else {
      int j = i - 49152;
      int l = j >> 14;
      int r = j & 16383;
      int c = r >> 8;
      int k256 = r & 255;
      int h = k256 & 3, kk = k256 >> 2;
      const float* W = (l == 0) ? W0 : (l == 1) ? W1 : W2;
      Wcat3[j] = __float2half(0.25f * W[(h * 64 + c) * 64 + kk]);
    }
    return;
  }
  if (b < 401) {
    int i = (b - 384) * 256 + t;
    if (i < GCNT * HID + GCNT) sums[i] = 0.f;
    return;
  }
  // ---- inproj path: 64 nodes/block, 4 threads/node, LDS-staged weights ----
  {
    __shared__ float Ws[1024];   // Win 64x16 row-major (j*16+k)
    __shared__ float vbs[128];
    __shared__ float bins[64];
    __shared__ float c8s[8];
    for (int i = t; i < 1024; i += 256) Ws[i] = Win[i];
    if (t < 128) vbs[t] = vb[t];
    if (t < 64) bins[t] = bin[t];
    if (t < 8) c8s[t] = c8[t];
    __syncthreads();
    int b2 = b - 401;
    int n = b2 * 64 + (t >> 2);
    int p = t & 3;
    if (n >= N) return;
    const float4* xr4 = (const float4*)(x + (size_t)n * F_IN);
    float4 a0 = xr4[0], a1 = xr4[1], a2 = xr4[2], a3 = xr4[3];
    float xv[16] = {a0.x, a0.y, a0.z, a0.w, a1.x, a1.y, a1.z, a1.w,
                    a2.x, a2.y, a2.z, a2.w, a3.x, a3.y, a3.z, a3.w};
    unsigned hv[8];
#pragma unroll
    for (int jj = 0; jj < 16; jj += 2) {
      int j = p * 16 + jj;
      float acc0 = bins[j], acc1 = bins[j + 1];
#pragma unroll
      for (int k = 0; k < 16; ++k) {
        acc0 = fmaf(xv[k], Ws[j * 16 + k], acc0);
        acc1 = fmaf(xv[k], Ws[(j + 1) * 16 + k], acc1);
      }
      hv[jj >> 1] = pack_h2(acc0, acc1);
    }
    uint4* dst = (uint4*)(hh + (size_t)n * 64 + p * 16);
    dst[0] = make_uint4(hv[0], hv[1], hv[2], hv[3]);
    dst[1] = make_uint4(hv[4], hv[5], hv[6], hv[7]);
    if (p == 0) {
      float sq[8];
#pragma unroll
      for (int q = 0; q < 8; ++q) {
        float s = c8s[q];
#pragma unroll
        for (int k = 0; k < 16; ++k) s = fmaf(xv[k], vbs[q * 16 + k], s);
        sq[q] = s;
      }
      *(float4*)(as_ + (size_t)n * 4) = make_float4(sq[0], sq[1], sq[2], sq[3]);
      *(float4*)(ad_ + (size_t)n * 4) = make_float4(sq[4], sq[5], sq[6], sq[7]);
    }
  }
}

// ---------------- CSR pass 2: per-bucket counting sort -> rowptr + col ----------------
__global__ __launch_bounds__(256) void k_bsort(
    const unsigned* __restrict__ tmp, const int* __restrict__ bcur,
    int* __restrict__ rowptr, int* __restrict__ col, int N) {
  __shared__ int s[NBUCK];
  __shared__ int hist[NBUCK];
  __shared__ int pref[NBUCK];
  int b = blockIdx.x, t = threadIdx.x;
  int c = min(bcur[t * BSTRIDE], BSLOT);
  s[t] = c;
  __syncthreads();
  for (int o = 1; o < 256; o <<= 1) {
    int x = (t >= o) ? s[t - o] : 0;
    __syncthreads();
    s[t] += x;
    __syncthreads();
  }
  int base = (b == 0) ? 0 : s[b - 1];
  int total = s[255];
  int cntb = min(bcur[b * BSTRIDE], BSLOT);
  hist[t] = 0;
  __syncthreads();
  for (int j = t; j < cntb; j += 256)
    atomicAdd(&hist[(tmp[(size_t)b * BSLOT + j] >> 16) & 255], 1);
  __syncthreads();
  int v = hist[t];
  pref[t] = v;
  __syncthreads();
  for (int o = 1; o < 256; o <<= 1) {
    int x = (t >= o) ? pref[t - o] : 0;
    __syncthreads();
    pref[t] += x;
    __syncthreads();
  }
  pref[t] -= v;
  __syncthreads();
  int node = b * 256 + t;
  if (node < N) rowptr[node] = base + pref[t];
  if (b == 255 && t == 255) rowptr[N] = total;
  hist[t] = 0;
  __syncthreads();
  for (int j = t; j < cntb; j += 256) {
    unsigned e = tmp[(size_t)b * BSLOT + j];
    int d8 = (int)((e >> 16) & 255);
    int r = atomicAdd(&hist[d8], 1);
    col[base + pref[d8] + r] = (int)(e & 0xffffu);
  }
}

// ---------------- single-node helper (any deg): writes one M row to LDS ----------------
__device__ __forceinline__ void gat_one_node(
    int node, int lane, const __half* __restrict__ h, const float* __restrict__ as_,
    const float* __restrict__ ad_, const int* __restrict__ rowptr,
    const int* __restrict__ col, __half* __restrict__ Mrow) {
  int r0 = rowptr[node];
  int deg = rowptr[node + 1] - r0;
  float4 adv = *(const float4*)(ad_ + (size_t)node * 4);

  if (deg <= 64) {
    int off = 0;
    float x0 = 0.f, x1 = 0.f, x2 = 0.f, x3 = 0.f;
    if (lane < deg) {
      int s = col[r0 + lane];
      off = s << 6;
      float4 av = *(const float4*)(as_ + (size_t)s * 4);
      float e0 = av.x + adv.x; e0 = (e0 > 0.f) ? e0 : NEG * e0;
      float e1 = av.y + adv.y; e1 = (e1 > 0.f) ? e1 : NEG * e1;
      float e2 = av.z + adv.z; e2 = (e2 > 0.f) ? e2 : NEG * e2;
      float e3 = av.w + adv.w; e3 = (e3 > 0.f) ? e3 : NEG * e3;
      x0 = __expf(fminf(e0, 60.f));
      x1 = __expf(fminf(e1, 60.f));
      x2 = __expf(fminf(e2, 60.f));
      x3 = __expf(fminf(e3, 60.f));
    }
    float s0 = x0, s1 = x1, s2 = x2, s3 = x3;
#pragma unroll
    for (int o = 32; o; o >>= 1) {
      s0 += __shfl_xor(s0, o, 64);
      s1 += __shfl_xor(s1, o, 64);
      s2 += __shfl_xor(s2, o, 64);
      s3 += __shfl_xor(s3, o, 64);
    }
    unsigned w01 = pack_h2(x0 / (s0 + 1e-16f), x1 / (s1 + 1e-16f));
    unsigned w23 = pack_h2(x2 / (s2 + 1e-16f), x3 / (s3 + 1e-16f));
    __half2 acc01 = __floats2half2_rn(0.f, 0.f);
    __half2 acc23 = acc01;
#pragma unroll 4
    for (int j = 0; j < deg; ++j) {
      int oj = __builtin_amdgcn_readlane(off, j) + lane;
      unsigned W01 = __builtin_amdgcn_readlane(w01, j);
      unsigned W23 = __builtin_amdgcn_readlane(w23, j);
      __half2 hv = __half2half2(h[oj]);
      acc01 = __hfma2(hv, uas_h2(W01), acc01);
      acc23 = __hfma2(hv, uas_h2(W23), acc23);
    }
    *(__half2*)&Mrow[lane * 4] = acc01;
    *(__half2*)&Mrow[lane * 4 + 2] = acc23;
    return;
  }
  float m0 = -1e30f, m1 = -1e30f, m2 = -1e30f, m3 = -1e30f;
  for (int j = lane; j < deg; j += 64) {
    int s = col[r0 + j];
    float4 av = *(const float4*)(as_ + (size_t)s * 4);
    float e0 = av.x + adv.x; e0 = (e0 > 0.f) ? e0 : NEG * e0; m0 = fmaxf(m0, e0);
    float e1 = av.y + adv.y; e1 = (e1 > 0.f) ? e1 : NEG * e1; m1 = fmaxf(m1, e1);
    float e2 = av.z + adv.z; e2 = (e2 > 0.f) ? e2 : NEG * e2; m2 = fmaxf(m2, e2);
    float e3 = av.w + adv.w; e3 = (e3 > 0.f) ? e3 : NEG * e3; m3 = fmaxf(m3, e3);
  }
#pragma unroll
  for (int o = 32; o; o >>= 1) {
    m0 = fmaxf(m0, __shfl_xor(m0, o, 64));
    m1 = fmaxf(m1, __shfl_xor(m1, o, 64));
    m2 = fmaxf(m2, __shfl_xor(m2, o, 64));
    m3 = fmaxf(m3, __shfl_xor(m3, o, 64));
  }
  float s0 = 0.f, s1 = 0.f, s2 = 0.f, s3 = 0.f;
  for (int j = lane; j < deg; j += 64) {
    int s = col[r0 + j];
    float4 av = *(const float4*)(as_ + (size_t)s * 4);
    float e0 = av.x + adv.x; e0 = (e0 > 0.f) ? e0 : NEG * e0; s0 += __expf(e0 - m0);
    float e1 = av.y + adv.y; e1 = (e1 > 0.f) ? e1 : NEG * e1; s1 += __expf(e1 - m1);
    float e2 = av.z + adv.z; e2 = (e2 > 0.f) ? e2 : NEG * e2; s2 += __expf(e2 - m2);
    float e3 = av.w + adv.w; e3 = (e3 > 0.f) ? e3 : NEG * e3; s3 += __expf(e3 - m3);
  }
#pragma unroll
  for (int o = 32; o; o >>= 1) {
    s0 += __shfl_xor(s0, o, 64);
    s1 += __shfl_xor(s1, o, 64);
    s2 += __shfl_xor(s2, o, 64);
    s3 += __shfl_xor(s3, o, 64);
  }
  float i0 = 1.f / (s0 + 1e-16f), i1 = 1.f / (s1 + 1e-16f);
  float i2 = 1.f / (s2 + 1e-16f), i3 = 1.f / (s3 + 1e-16f);
  float a0 = 0.f, a1 = 0.f, a2 = 0.f, a3 = 0.f;
  for (int j = 0; j < deg; ++j) {
    int s = col[r0 + j];
    float4 av = *(const float4*)(as_ + (size_t)s * 4);
    float e0 = av.x + adv.x; e0 = (e0 > 0.f) ? e0 : NEG * e0;
    float e1 = av.y + adv.y; e1 = (e1 > 0.f) ? e1 : NEG * e1;
    float e2 = av.z + adv.z; e2 = (e2 > 0.f) ? e2 : NEG * e2;
    float e3 = av.w + adv.w; e3 = (e3 > 0.f) ? e3 : NEG * e3;
    float hv = __half2float(h[(s << 6) + lane]);
    a0 = fmaf(__expf(e0 - m0) * i0, hv, a0);
    a1 = fmaf(__expf(e1 - m1) * i1, hv, a1);
    a2 = fmaf(__expf(e2 - m2) * i2, hv, a2);
    a3 = fmaf(__expf(e3 - m3) * i3, hv, a3);
  }
  *(__half2*)&Mrow[lane * 4] = __floats2half2_rn(a0, a1);
  *(__half2*)&Mrow[lane * 4 + 2] = __floats2half2_rn(a2, a3);
}

// ---------------- one pair (serial path; handles slow cases) ----------------
__device__ __forceinline__ void gat_pair(
    int pr, int lane, int half, int l5, int N,
    const __half* __restrict__ h, const float* __restrict__ as_,
    const float* __restrict__ ad_, const int* __restrict__ rowptr,
    const int* __restrict__ col, __half* __restrict__ Mt) {
  int n0 = pr * 2;
  int n1 = min(n0 + 1, N - 1);
  int mynode = half ? n1 : n0;
  int r0 = rowptr[mynode];
  int dg = rowptr[mynode + 1] - r0;
  int dgA = __builtin_amdgcn_readlane(dg, 0);
  int dgB = __builtin_amdgcn_readlane(dg, 32);

  if (dgA <= 32 && dgB <= 32) {
    float4 adv = *(const float4*)(ad_ + (size_t)mynode * 4);
    int off = 0;
    float x0 = 0.f, x1 = 0.f, x2 = 0.f, x3 = 0.f;
    if (l5 < dg) {
      int s = col[r0 + l5];
      off = s << 6;
      float4 av = *(const float4*)(as_ + (size_t)s * 4);
      float e0 = av.x + adv.x; e0 = (e0 > 0.f) ? e0 : NEG * e0;
      float e1 = av.y + adv.y; e1 = (e1 > 0.f) ? e1 : NEG * e1;
      float e2 = av.z + adv.z; e2 = (e2 > 0.f) ? e2 : NEG * e2;
      float e3 = av.w + adv.w; e3 = (e3 > 0.f) ? e3 : NEG * e3;
      x0 = __expf(fminf(e0, 60.f));
      x1 = __expf(fminf(e1, 60.f));
      x2 = __expf(fminf(e2, 60.f));
      x3 = __expf(fminf(e3, 60.f));
    }
    float s0 = x0, s1 = x1, s2 = x2, s3 = x3;
#pragma unroll
    for (int o = 16; o; o >>= 1) {
      s0 += __shfl_xor(s0, o, 64);
      s1 += __shfl_xor(s1, o, 64);
      s2 += __shfl_xor(s2, o, 64);
      s3 += __shfl_xor(s3, o, 64);
    }
    unsigned w01 = pack_h2(x0 / (s0 + 1e-16f), x1 / (s1 + 1e-16f));
    unsigned w23 = pack_h2(x2 / (s2 + 1e-16f), x3 / (s3 + 1e-16f));

    int g = l5 >> 4, li = l5 & 15;
    const uint2* h4p = (const uint2*)h;
    __half2 z = __floats2half2_rn(0.f, 0.f);
    __half2 a0_01 = z, a0_23 = z, a1_01 = z, a1_23 = z;
    __half2 a2_01 = z, a2_23 = z, a3_01 = z, a3_23 = z;
    int mdeg = max(dgA, dgB);
    int baddr = half << 7;
#pragma unroll 2
    for (int j = 0; j < mdeg; j += 2) {
      int addr = baddr + (j + g) * 4;
      int oj = __builtin_amdgcn_ds_bpermute(addr, off);
      unsigned W01 = (unsigned)__builtin_amdgcn_ds_bpermute(addr, (int)w01);
      unsigned W23 = (unsigned)__builtin_amdgcn_ds_bpermute(addr, (int)w23);
      uint2 hv = h4p[(oj >> 2) + li];
      __half2 ha = uas_h2(hv.x), hb = uas_h2(hv.y);
      __half2 wA = uas_h2(W01), wB = uas_h2(W23);
      __half2 c0 = __low2half2(ha), c1 = __high2half2(ha);
      __half2 c2 = __low2half2(hb), c3 = __high2half2(hb);
      a0_01 = __hfma2(c0, wA, a0_01); a0_23 = __hfma2(c0, wB, a0_23);
      a1_01 = __hfma2(c1, wA, a1_01); a1_23 = __hfma2(c1, wB, a1_23);
      a2_01 = __hfma2(c2, wA, a2_01); a2_23 = __hfma2(c2, wB, a2_23);
      a3_01 = __hfma2(c3, wA, a3_01); a3_23 = __hfma2(c3, wB, a3_23);
    }
    a0_01 = xor16_add(a0_01); a0_23 = xor16_add(a0_23);
    a1_01 = xor16_add(a1_01); a1_23 = xor16_add(a1_23);
    a2_01 = xor16_add(a2_01); a2_23 = xor16_add(a2_23);
    a3_01 = xor16_add(a3_01); a3_23 = xor16_add(a3_23);
    if (g == 0) {
      __half* row = &Mt[(mynode & 15) * 264 + li * 16];
      uint4 st1, st2;
      st1.x = h2_as_u(a0_01); st1.y = h2_as_u(a0_23);
      st1.z = h2_as_u(a1_01); st1.w = h2_as_u(a1_23);
      st2.x = h2_as_u(a2_01); st2.y = h2_as_u(a2_23);
      st2.z = h2_as_u(a3_01); st2.w = h2_as_u(a3_23);
      *(uint4*)&row[0] = st1;
      *(uint4*)&row[8] = st2;
    }
  } else {
    gat_one_node(n0, lane, h, as_, ad_, rowptr, col, &Mt[(n0 & 15) * 264]);
    if (n1 != n0) gat_one_node(n1, lane, h, as_, ad_, rowptr, col, &Mt[(n1 & 15) * 264]);
  }
}

// ---------------- fused GAT layer: proven round-3 structure ----------------
template <bool FIN>
__global__ __launch_bounds__(256) void k_gatf(
    const __half* __restrict__ h, const float* __restrict__ as_,
    const float* __restrict__ ad_, const int* __restrict__ rowptr,
    const int* __restrict__ col, const __half* __restrict__ Wcat,
    const float* __restrict__ bg, const __half* __restrict__ Wn,
    const float* __restrict__ asrc, const float* __restrict__ adst,
    __half* __restrict__ hout, float* __restrict__ nas, float* __restrict__ nad,
    const int* __restrict__ batchv, float* __restrict__ gsums,
    int N) {
  __shared__ __half Mt[16 * 264];
  __shared__ __half O[16 * 72];
  int tid = threadIdx.x;
  int lane = tid & 63, wv = tid >> 6;
  int tile = blockIdx.x;
  int half = lane >> 5, l5 = lane & 31;
  int npairs = (N + 1) >> 1;

  // ---- phase 1: two pairs per wave; edge records staged in this wave's Mt rows ----
  int pr0 = tile * 8 + wv * 2;
  int pr1 = pr0 + 1;
  bool has0 = pr0 < npairs, has1 = pr1 < npairs;
  if (has0 && has1) {
    int my0 = min(pr0 * 2 + half, N - 1);
    int my1 = min(pr1 * 2 + half, N - 1);
    int r0a = rowptr[my0];
    int dga = rowptr[my0 + 1] - r0a;
    int r0b = rowptr[my1];
    int dgb = rowptr[my1 + 1] - r0b;
    int dA0 = __builtin_amdgcn_readlane(dga, 0);
    int dB0 = __builtin_amdgcn_readlane(dga, 32);
    int dA1 = __builtin_amdgcn_readlane(dgb, 0);
    int dB1 = __builtin_amdgcn_readlane(dgb, 32);

    if (dA0 <= 32 && dB0 <= 32 && dA1 <= 32 && dB1 <= 32) {
      float4 adva = *(const float4*)(ad_ + (size_t)my0 * 4);
      float4 advb = *(const float4*)(ad_ + (size_t)my1 * 4);
      int offa = 0, offb = 0;
      float xa0 = 0.f, xa1 = 0.f, xa2 = 0.f, xa3 = 0.f;
      float xb0 = 0.f, xb1 = 0.f, xb2 = 0.f, xb3 = 0.f;
      if (l5 < dga) {
        int s = col[r0a + l5];
        offa = s << 6;
        float4 av = *(const float4*)(as_ + (size_t)s * 4);
        float e0 = av.x + adva.x; e0 = (e0 > 0.f) ? e0 : NEG * e0;
        float e1 = av.y + adva.y; e1 = (e1 > 0.f) ? e1 : NEG * e1;
        float e2 = av.z + adva.z; e2 = (e2 > 0.f) ? e2 : NEG * e2;
        float e3 = av.w + adva.w; e3 = (e3 > 0.f) ? e3 : NEG * e3;
        xa0 = __expf(fminf(e0, 60.f));
        xa1 = __expf(fminf(e1, 60.f));
        xa2 = __expf(fminf(e2, 60.f));
        xa3 = __expf(fminf(e3, 60.f));
      }
      if (l5 < dgb) {
        int s = col[r0b + l5];
        offb = s << 6;
        float4 av = *(const float4*)(as_ + (size_t)s * 4);
        float e0 = av.x + advb.x; e0 = (e0 > 0.f) ? e0 : NEG * e0;
        float e1 = av.y + advb.y; e1 = (e1 > 0.f) ? e1 : NEG * e1;
        float e2 = av.z + advb.z; e2 = (e2 > 0.f) ? e2 : NEG * e2;
        float e3 = av.w + advb.w; e3 = (e3 > 0.f) ? e3 : NEG * e3;
        xb0 = __expf(fminf(e0, 60.f));
        xb1 = __expf(fminf(e1, 60.f));
        xb2 = __expf(fminf(e2, 60.f));
        xb3 = __expf(fminf(e3, 60.f));
      }
      float sa0 = xa0, sa1 = xa1, sa2 = xa2, sa3 = xa3;
      float sb0 = xb0, sb1 = xb1, sb2 = xb2, sb3 = xb3;
#pragma unroll
      for (int o = 16; o; o >>= 1) {
        sa0 += __shfl_xor(sa0, o, 64);
        sa1 += __shfl_xor(sa1, o, 64);
        sa2 += __shfl_xor(sa2, o, 64);
        sa3 += __shfl_xor(sa3, o, 64);
        sb0 += __shfl_xor(sb0, o, 64);
        sb1 += __shfl_xor(sb1, o, 64);
        sb2 += __shfl_xor(sb2, o, 64);
        sb3 += __shfl_xor(sb3, o, 64);
      }
      unsigned w01a = pack_h2(xa0 / (sa0 + 1e-16f), xa1 / (sa1 + 1e-16f));
      unsigned w23a = pack_h2(xa2 / (sa2 + 1e-16f), xa3 / (sa3 + 1e-16f));
      unsigned w01b = pack_h2(xb0 / (sb0 + 1e-16f), xb1 / (sb1 + 1e-16f));
      unsigned w23b = pack_h2(xb2 / (sb2 + 1e-16f), xb3 / (sb3 + 1e-16f));

      // stage edge records in this wave's 4 Mt rows (aliased; consumed before Mt write)
      uint4* EB = (uint4*)&Mt[wv * 1056];  // 4 rows x 264 halves = 2112 B >= 2048 B
      EB[half * 32 + l5] = make_uint4((unsigned)offa, w01a, w23a, 0u);
      EB[64 + half * 32 + l5] = make_uint4((unsigned)offb, w01b, w23b, 0u);

      int g = l5 >> 4, li = l5 & 15;
      const uint2* h4p = (const uint2*)h;
      __half2 z = __floats2half2_rn(0.f, 0.f);
      __half2 pa0 = z, pa1 = z, pa2 = z, pa3 = z, pa4 = z, pa5 = z, pa6 = z, pa7 = z;
      __half2 pb0 = z, pb1 = z, pb2 = z, pb3 = z, pb4 = z, pb5 = z, pb6 = z, pb7 = z;
      int mm = max(max(dA0, dB0), max(dA1, dB1));
      int ebase = half * 32;
#pragma unroll 2
      for (int j = 0; j < mm; j += 2) {
        uint4 ra = EB[ebase + j + g];        // broadcast read (1 addr per 16-lane group)
        uint4 rb = EB[64 + ebase + j + g];
        uint2 hva = h4p[((int)ra.x >> 2) + li];
        uint2 hvb = h4p[((int)rb.x >> 2) + li];
        {
          __half2 ha = uas_h2(hva.x), hb = uas_h2(hva.y);
          __half2 wA = uas_h2(ra.y), wB = uas_h2(ra.z);
          __half2 c0 = __low2half2(ha), c1 = __high2half2(ha);
          __half2 c2 = __low2half2(hb), c3 = __high2half2(hb);
          pa0 = __hfma2(c0, wA, pa0); pa1 = __hfma2(c0, wB, pa1);
          pa2 = __hfma2(c1, wA, pa2); pa3 = __hfma2(c1, wB, pa3);
          pa4 = __hfma2(c2, wA, pa4); pa5 = __hfma2(c2, wB, pa5);
          pa6 = __hfma2(c3, wA, pa6); pa7 = __hfma2(c3, wB, pa7);
        }
        {
          __half2 ha = uas_h2(hvb.x), hb = uas_h2(hvb.y);
          __half2 wA = uas_h2(rb.y), wB = uas_h2(rb.z);
          __half2 c0 = __low2half2(ha), c1 = __high2half2(ha);
          __half2 c2 = __low2half2(hb), c3 = __high2half2(hb);
          pb0 = __hfma2(c0, wA, pb0); pb1 = __hfma2(c0, wB, pb1);
          pb2 = __hfma2(c1, wA, pb2); pb3 = __hfma2(c1, wB, pb3);
          pb4 = __hfma2(c2, wA, pb4); pb5 = __hfma2(c2, wB, pb5);
          pb6 = __hfma2(c3, wA, pb6); pb7 = __hfma2(c3, wB, pb7);
        }
      }
      pa0 = xor16_add(pa0); pa1 = xor16_add(pa1); pa2 = xor16_add(pa2); pa3 = xor16_add(pa3);
      pa4 = xor16_add(pa4); pa5 = xor16_add(pa5); pa6 = xor16_add(pa6); pa7 = xor16_add(pa7);
      pb0 = xor16_add(pb0); pb1 = xor16_add(pb1); pb2 = xor16_add(pb2); pb3 = xor16_add(pb3);
      pb4 = xor16_add(pb4); pb5 = xor16_add(pb5); pb6 = xor16_add(pb6); pb7 = xor16_add(pb7);
      if (g == 0) {
        __half* rowA = &Mt[(my0 & 15) * 264 + li * 16];
        __half* rowB = &Mt[(my1 & 15) * 264 + li * 16];
        uint4 s1, s2;
        s1.x = h2_as_u(pa0); s1.y = h2_as_u(pa1); s1.z = h2_as_u(pa2); s1.w = h2_as_u(pa3);
        s2.x = h2_as_u(pa4); s2.y = h2_as_u(pa5); s2.z = h2_as_u(pa6); s2.w = h2_as_u(pa7);
        *(uint4*)&rowA[0] = s1;
        *(uint4*)&rowA[8] = s2;
        s1.x = h2_as_u(pb0); s1.y = h2_as_u(pb1); s1.z = h2_as_u(pb2); s1.w = h2_as_u(pb3);
        s2.x = h2_as_u(pb4); s2.y = h2_as_u(pb5); s2.z = h2_as_u(pb6); s2.w = h2_as_u(pb7);
        *(uint4*)&rowB[0] = s1;
        *(uint4*)&rowB[8] = s2;
      }
    } else {
      gat_pair(pr0, lane, half, l5, N, h, as_, ad_, rowptr, col, Mt);
      gat_pair(pr1, lane, half, l5, N, h, as_, ad_, rowptr, col, Mt);
    }
  } else if (has0) {
    gat_pair(pr0, lane, half, l5, N, h, as_, ad_, rowptr, col, Mt);
  }
  __syncthreads();

  // ---- phase 2: head-mean GEMM (+ next-layer attn scalars, or LDS-staged graph-pool) ----
  int quad = lane >> 4, n16 = lane & 15;
  const f16x8* WC = (const f16x8*)Wcat;
  int ch1 = wv * 16 + n16;
  float bias1 = bg[ch1];
  f32x4 c1 = {0.f, 0.f, 0.f, 0.f};
#pragma unroll
  for (int i = 0; i < 8; ++i) {
    f16x8 a = *(const f16x8*)&Mt[n16 * 264 + (i * 4 + quad) * 8];
    c1 = __builtin_amdgcn_mfma_f32_16x16x32_f16(a, WC[ch1 * 32 + i * 4 + quad], c1, 0, 0, 0);
  }
#pragma unroll
  for (int r = 0; r < 4; ++r) {
    float v = fmaxf(c1[r] + bias1, 0.f);
    O[(quad * 4 + r) * 72 + ch1] = __float2half(v);
  }
  __syncthreads();

  if (FIN) {
    // LDS-staged mean pool: 64 threads, one channel each
    if (tid < 64) {
      float* cnt_ = gsums + GCNT * HID;
      int c = tid;
      int nmax = min(16, N - tile * 16);
      int curg = -1;
      float acc = 0.f;
      int cacc = 0;
      for (int i = 0; i < nmax; ++i) {
        int gph = batchv[tile * 16 + i];
        float v = __half2float(O[i * 72 + c]);
        if (gph != curg) {
          if (curg >= 0) {
            atomicAdd(&gsums[curg * HID + c], acc);
            if (c == 0) atomicAdd(&cnt_[curg], (float)cacc);
          }
          curg = gph;
          acc = 0.f;
          cacc = 0;
        }
        acc += v;
        ++cacc;
      }
      if (curg >= 0) {
        atomicAdd(&gsums[curg * HID + c], acc);
        if (c == 0) atomicAdd(&cnt_[curg], (float)cacc);
      }
    }
    return;
  }

  {
    int nd = tid >> 4, c0 = (tid & 15) * 4;
    int node = tile * 16 + nd;
    if (node < N) {
      uint2 v = *(const uint2*)&O[nd * 72 + c0];
      *(uint2*)&hout[(size_t)node * 64 + c0] = v;
    }
  }
  {
    const f16x8* WN = (const f16x8*)Wn;
    f16x8 a0 = *(const f16x8*)&O[n16 * 72 + quad * 8];
    f16x8 a1 = *(const f16x8*)&O[n16 * 72 + 32 + quad * 8];
    f32x4 accs[4];
#pragma unroll
    for (int nt = 0; nt < 4; ++nt) {
      int ch = wv * 64 + nt * 16 + n16;
      f32x4 zz = {0.f, 0.f, 0.f, 0.f};
      zz = __builtin_amdgcn_mfma_f32_16x16x32_f16(a0, WN[ch * 8 + quad], zz, 0, 0, 0);
      zz = __builtin_amdgcn_mfma_f32_16x16x32_f16(a1, WN[ch * 8 + 4 + quad], zz, 0, 0, 0);
      accs[nt] = zz;
    }
#pragma unroll
    for (int r = 0; r < 4; ++r) {
      float vs = 0.f, vd = 0.f;
#pragma unroll
      for (int nt = 0; nt < 4; ++nt) {
        int ch = wv * 64 + nt * 16 + n16;
        vs = fmaf(accs[nt][r], asrc[ch], vs);
        vd = fmaf(accs[nt][r], adst[ch], vd);
      }
#pragma unroll
      for (int o = 8; o; o >>= 1) {
        vs += __shfl_xor(vs, o, 64);
        vd += __shfl_xor(vd, o, 64);
      }
      int node = tile * 16 + quad * 4 + r;
      if (n16 == 0 && node < N) {
        nas[(size_t)node * 4 + wv] = vs;
        nad[(size_t)node * 4 + wv] = vd;
      }
    }
  }
}

// ---------------- readout ----------------
__global__ void k_out(const float* __restrict__ sums, const float* __restrict__ cnt,
                      const float* __restrict__ Wout, const float* __restrict__ bout,
                      float* __restrict__ out) {
  int g = blockIdx.x, lane = threadIdx.x;
  float cg = fmaxf(cnt[g], 1.f);
  float v = (sums[g * HID + lane] / cg) * Wout[lane];
#pragma unroll
  for (int o = 32; o; o >>= 1) v += __shfl_xor(v, o, 64);
  if (lane == 0) out[g] = 1.f / (1.f + __expf(-v));
}

extern "C" void kernel_launch(void* const* d_in, const int* in_sizes, int n_in,
                              void* d_out, int out_size, void* d_ws, size_t ws_size,
                              hipStream_t stream) {
  const float* x    = (const float*)d_in[0];
  const int*   ei   = (const int*)d_in[1];
  const int*   batch= (const int*)d_in[2];
  const float* Win  = (const float*)d_in[3];
  const float* bin  = (const float*)d_in[4];
  const float* Wout = (const float*)d_in[5];
  const float* bout = (const float*)d_in[6];
  const float* Wl[3]    = {(const float*)d_in[7],  (const float*)d_in[11], (const float*)d_in[15]};
  const float* asrcl[3] = {(const float*)d_in[8],  (const float*)d_in[12], (const float*)d_in[16]};
  const float* adstl[3] = {(const float*)d_in[9],  (const float*)d_in[13], (const float*)d_in[17]};
  const float* bgl[3]   = {(const float*)d_in[10], (const float*)d_in[14], (const float*)d_in[18]};

  int N = in_sizes[2];       // 50000
  int E = in_sizes[1] / 2;   // 800000
  int EE = E + N;

  char* p = (char*)d_ws;
  auto alloc = [&](size_t bytes) {
    char* r = p;
    p += (bytes + 255) & ~(size_t)255;
    return r;
  };
  int*      rowptr = (int*)alloc((size_t)(N + 1) * 4);
  int*      col    = (int*)alloc((size_t)EE * 4);
  unsigned* tmp    = (unsigned*)alloc((size_t)NBUCK * BSLOT * 4);
  int*      bcur   = (int*)alloc((size_t)NBUCK * BSTRIDE * 4);
  float*    vb     = (float*)alloc(128 * 4);
  float*    c8     = (float*)alloc(8 * 4);
  __half*   hhA    = (__half*)alloc((size_t)N * HID * 2);
  __half*   hhB    = (__half*)alloc((size_t)N * HID * 2);
  float*    asA    = (float*)alloc((size_t)N * HEADS * 4);
  float*    adA    = (float*)alloc((size_t)N * HEADS * 4);
  float*    asB    = (float*)alloc((size_t)N * HEADS * 4);
  float*    adB    = (float*)alloc((size_t)N * HEADS * 4);
  __half*   Wh3    = (__half*)alloc(3 * 16384 * 2);
  __half*   Wcat3  = (__half*)alloc(3 * 16384 * 2);
  float*    sums   = (float*)alloc((size_t)(GCNT * HID + GCNT) * 4);
  float*    cnt    = sums + GCNT * HID;

  int tiles = (N + 15) / 16;
  int BUK = (EE + SCHUNK - 1) / SCHUNK;
  int initB = 401 + (N + 63) / 64;   // weight-prep 384 + sums 17 + inproj (64 nodes/block)

  k_pre<<<2, 256, 0, stream>>>(Wl[0], asrcl[0], adstl[0], Win, bin, bcur, vb, c8);

  k_binit<<<BUK + initB, 256, 0, stream>>>(ei, bcur, tmp, E, N,
                                           x, Win, bin, Wl[0], Wl[1], Wl[2],
                                           Wh3, Wcat3, sums, vb, c8, asA, adA, hhA, BUK);

  k_bsort<<<NBUCK, 256, 0, stream>>>(tmp, bcur, rowptr, col, N);

  k_gatf<false><<<tiles, 256, 0, stream>>>(hhA, asA, adA, rowptr, col,
                                           Wcat3, bgl[0], Wh3 + 16384, asrcl[1], adstl[1],
                                           hhB, asB, adB, nullptr, nullptr, N);
  k_gatf<false><<<tiles, 256, 0, stream>>>(hhB, asB, adB, rowptr, col,
                                           Wcat3 + 16384, bgl[1], Wh3 + 32768, asrcl[2], adstl[2],
                                           hhA, asA, adA, nullptr, nullptr, N);
  k_gatf<true><<<tiles, 256, 0, stream>>>(hhA, asA, adA, rowptr, col,
                                          Wcat3 + 32768, bgl[2], nullptr, nullptr, nullptr,
                                          nullptr, nullptr, nullptr, batch, sums, N);

  k_out<<<GCNT, 64, 0, stream>>>(sums, cnt, Wout, bout, (float*)d_out);
}

// Round 10
// 289.081 us; speedup vs baseline: 1.2641x; 1.0230x over previous
//
#include <hip/hip_runtime.h>
#include <hip/hip_bf16.h>
#include <hip/hip_fp16.h>

#define HID 64
#define HEADS 4
#define GCNT 64
#define F_IN 16
#define NEG 0.2f
#define NBUCK 256
#define BSLOT 6144
#define SCHUNK 2048
#define BSTRIDE 16  // bcur counters padded to one per 64B line (atomic-line serialization fix)

typedef _Float16 f16x8 __attribute__((ext_vector_type(8)));
typedef float f32x4 __attribute__((ext_vector_type(4)));

__device__ __forceinline__ unsigned pack_h2(float a, float b) {
  __half2 h = __floats2half2_rn(a, b);
  union { __half2 h; unsigned u; } c;
  c.h = h;
  return c.u;
}
__device__ __forceinline__ __half2 uas_h2(unsigned u) {
  union { unsigned u; __half2 h; } c;
  c.u = u;
  return c.h;
}
__device__ __forceinline__ unsigned h2_as_u(__half2 h) {
  union { __half2 h; unsigned u; } c;
  c.h = h;
  return c.u;
}
__device__ __forceinline__ __half2 xor16_add(__half2 v) {
  unsigned u = (unsigned)__shfl_xor((int)h2_as_u(v), 16, 64);
  return __hadd2(v, uas_h2(u));
}

// one gathered h-row fragment (uint2 = 4 halfs) x edge weights (2 half2) -> 8 accum half2
#define FMA_REC(HV, W01, W23, P0, P1, P2, P3, P4, P5, P6, P7)      \
  do {                                                             \
    __half2 _ha = uas_h2((HV).x), _hb = uas_h2((HV).y);            \
    __half2 _wA = uas_h2(W01), _wB = uas_h2(W23);                  \
    __half2 _c0 = __low2half2(_ha), _c1 = __high2half2(_ha);       \
    __half2 _c2 = __low2half2(_hb), _c3 = __high2half2(_hb);       \
    P0 = __hfma2(_c0, _wA, P0); P1 = __hfma2(_c0, _wB, P1);        \
    P2 = __hfma2(_c1, _wA, P2); P3 = __hfma2(_c1, _wB, P3);        \
    P4 = __hfma2(_c2, _wA, P4); P5 = __hfma2(_c2, _wB, P5);        \
    P6 = __hfma2(_c3, _wA, P6); P7 = __hfma2(_c3, _wB, P7);        \
  } while (0)

// ---------------- pre: zero padded bucket cursors + fold layer-0 attn through Win ----------------
__global__ __launch_bounds__(256) void k_pre(
    const float* __restrict__ W0, const float* __restrict__ asrc,
    const float* __restrict__ adst, const float* __restrict__ Win,
    const float* __restrict__ bin, int* __restrict__ bcur,
    float* __restrict__ vb, float* __restrict__ c8) {
  int t = threadIdx.x;
  if (blockIdx.x == 0) {
    for (int i = t; i < NBUCK * BSTRIDE; i += 256) bcur[i] = 0;
    return;
  }
  __shared__ float vaL[512];
#pragma unroll
  for (int it = 0; it < 2; ++it) {
    int idx = t + it * 256;
    int q = idx >> 6, j = idx & 63;
    const float* a = (q < 4) ? asrc : adst;
    int h = q & 3;
    float s = 0.f;
    for (int c = 0; c < 64; ++c) s += a[h * 64 + c] * W0[(h * 64 + c) * 64 + j];
    vaL[idx] = s;
  }
  __syncthreads();
  if (t < 128) {
    int q = t >> 4, k = t & 15;
    float s = 0.f;
    for (int j = 0; j < 64; ++j) s += vaL[q * 64 + j] * Win[j * F_IN + k];
    vb[t] = s;
  } else if (t < 136) {
    int q = t - 128;
    float s = 0.f;
    for (int j = 0; j < 64; ++j) s += vaL[q * 64 + j] * bin[j];
    c8[q] = s;
  }
}

// ---------------- fused: CSR pass 1 (bucket) + weight prep + LDS-staged inproj ----------------
__global__ __launch_bounds__(256) void k_binit(
    const int* __restrict__ ei, int* __restrict__ bcur,
    unsigned* __restrict__ tmp, int E, int N,
    const float* __restrict__ x, const float* __restrict__ Win,
    const float* __restrict__ bin,
    const float* __restrict__ W0, const float* __restrict__ W1,
    const float* __restrict__ W2,
    __half* __restrict__ Wh3, __half* __restrict__ Wcat3,
    float* __restrict__ sums, const float* __restrict__ vb,
    const float* __restrict__ c8,
    float* __restrict__ as_, float* __restrict__ ad_,
    __half* __restrict__ hh, int BUK) {
  int t = threadIdx.x;
  if (blockIdx.x < BUK) {
    // ---- bucket path ----
    __shared__ int hist[NBUCK];
    __shared__ int base[NBUCK];
    int start = blockIdx.x * SCHUNK;
    int end = min(start + SCHUNK, E + N);
    hist[t] = 0;
    __syncthreads();
    unsigned val[8];
    int rank[8];
    bool ok[8];
#pragma unroll
    for (int k = 0; k < 8; ++k) {
      int i = start + t + k * 256;
      ok[k] = i < end;
      if (ok[k]) {
        int s, d;
        if (i < E) {
          s = ei[i];
          d = ei[E + i];
        } else {
          s = d = i - E;
        }
        val[k] = ((unsigned)d << 16) | (unsigned)s;
        rank[k] = atomicAdd(&hist[d >> 8], 1);
      }
    }
    __syncthreads();
    int h = hist[t];
    // padded counters: one atomic per 64B line -> no same-line serialization
    base[t] = h ? atomicAdd(&bcur[t * BSTRIDE], h) : 0;
    __syncthreads();
#pragma unroll
    for (int k = 0; k < 8; ++k) {
      if (ok[k]) {
        int bk = (int)(val[k] >> 24);
        int idx = base[bk] + rank[k];
        if (idx < BSLOT) tmp[(size_t)bk * BSLOT + idx] = val[k];
      }
    }
    return;
  }
  // ---- weight prep / zero path ----
  int b = blockIdx.x - BUK;
  if (b < 384) {
    int i = b * 256 + t;
    if (i < 49152) {
      const float* W = (i < 16384) ? W0 : (i < 32768) ? W1 : W2;
      Wh3[i] = __float2half(W[i & 16383]);
    } else {
      int j = i - 49152;
      int l = j >> 14;
      int r = j & 16383;
      int c = r >> 8;
      int k256 = r & 255;
      int h = k256 & 3, kk = k256 >> 2;
      const float* W = (l == 0) ? W0 : (l == 1) ? W1 : W2;
      Wcat3[j] = __float2half(0.25f * W[(h * 64 + c) * 64 + kk]);
    }
    return;
  }
  if (b < 401) {
    int i = (b - 384) * 256 + t;
    if (i < GCNT * HID + GCNT) sums[i] = 0.f;
    return;
  }
  // ---- inproj path: 64 nodes/block, 4 threads/node, LDS-staged weights ----
  {
    __shared__ float Ws[1024];   // Win 64x16 row-major (j*16+k)
    __shared__ float vbs[128];
    __shared__ float bins[64];
    __shared__ float c8s[8];
    for (int i = t; i < 1024; i += 256) Ws[i] = Win[i];
    if (t < 128) vbs[t] = vb[t];
    if (t < 64) bins[t] = bin[t];
    if (t < 8) c8s[t] = c8[t];
    __syncthreads();
    int b2 = b - 401;
    int n = b2 * 64 + (t >> 2);
    int p = t & 3;
    if (n >= N) return;
    const float4* xr4 = (const float4*)(x + (size_t)n * F_IN);
    float4 a0 = xr4[0], a1 = xr4[1], a2 = xr4[2], a3 = xr4[3];
    float xv[16] = {a0.x, a0.y, a0.z, a0.w, a1.x, a1.y, a1.z, a1.w,
                    a2.x, a2.y, a2.z, a2.w, a3.x, a3.y, a3.z, a3.w};
    unsigned hv[8];
#pragma unroll
    for (int jj = 0; jj < 16; jj += 2) {
      int j = p * 16 + jj;
      float acc0 = bins[j], acc1 = bins[j + 1];
#pragma unroll
      for (int k = 0; k < 16; ++k) {
        acc0 = fmaf(xv[k], Ws[j * 16 + k], acc0);
        acc1 = fmaf(xv[k], Ws[(j + 1) * 16 + k], acc1);
      }
      hv[jj >> 1] = pack_h2(acc0, acc1);
    }
    uint4* dst = (uint4*)(hh + (size_t)n * 64 + p * 16);
    dst[0] = make_uint4(hv[0], hv[1], hv[2], hv[3]);
    dst[1] = make_uint4(hv[4], hv[5], hv[6], hv[7]);
    if (p == 0) {
      float sq[8];
#pragma unroll
      for (int q = 0; q < 8; ++q) {
        float s = c8s[q];
#pragma unroll
        for (int k = 0; k < 16; ++k) s = fmaf(xv[k], vbs[q * 16 + k], s);
        sq[q] = s;
      }
      *(float4*)(as_ + (size_t)n * 4) = make_float4(sq[0], sq[1], sq[2], sq[3]);
      *(float4*)(ad_ + (size_t)n * 4) = make_float4(sq[4], sq[5], sq[6], sq[7]);
    }
  }
}

// ---------------- CSR pass 2: per-bucket counting sort -> rowptr + col ----------------
__global__ __launch_bounds__(256) void k_bsort(
    const unsigned* __restrict__ tmp, const int* __restrict__ bcur,
    int* __restrict__ rowptr, int* __restrict__ col, int N) {
  __shared__ int s[NBUCK];
  __shared__ int hist[NBUCK];
  __shared__ int pref[NBUCK];
  int b = blockIdx.x, t = threadIdx.x;
  int c = min(bcur[t * BSTRIDE], BSLOT);
  s[t] = c;
  __syncthreads();
  for (int o = 1; o < 256; o <<= 1) {
    int x = (t >= o) ? s[t - o] : 0;
    __syncthreads();
    s[t] += x;
    __syncthreads();
  }
  int base = (b == 0) ? 0 : s[b - 1];
  int total = s[255];
  int cntb = min(bcur[b * BSTRIDE], BSLOT);
  hist[t] = 0;
  __syncthreads();
  for (int j = t; j < cntb; j += 256)
    atomicAdd(&hist[(tmp[(size_t)b * BSLOT + j] >> 16) & 255], 1);
  __syncthreads();
  int v = hist[t];
  pref[t] = v;
  __syncthreads();
  for (int o = 1; o < 256; o <<= 1) {
    int x = (t >= o) ? pref[t - o] : 0;
    __syncthreads();
    pref[t] += x;
    __syncthreads();
  }
  pref[t] -= v;
  __syncthreads();
  int node = b * 256 + t;
  if (node < N) rowptr[node] = base + pref[t];
  if (b == 255 && t == 255) rowptr[N] = total;
  hist[t] = 0;
  __syncthreads();
  for (int j = t; j < cntb; j += 256) {
    unsigned e = tmp[(size_t)b * BSLOT + j];
    int d8 = (int)((e >> 16) & 255);
    int r = atomicAdd(&hist[d8], 1);
    col[base + pref[d8] + r] = (int)(e & 0xffffu);
  }
}

// ---------------- single-node helper (any deg): writes one M row to LDS ----------------
__device__ __forceinline__ void gat_one_node(
    int node, int lane, const __half* __restrict__ h, const float* __restrict__ as_,
    const float* __restrict__ ad_, const int* __restrict__ rowptr,
    const int* __restrict__ col, __half* __restrict__ Mrow) {
  int r0 = rowptr[node];
  int deg = rowptr[node + 1] - r0;
  float4 adv = *(const float4*)(ad_ + (size_t)node * 4);

  if (deg <= 64) {
    int off = 0;
    float x0 = 0.f, x1 = 0.f, x2 = 0.f, x3 = 0.f;
    if (lane < deg) {
      int s = col[r0 + lane];
      off = s << 6;
      float4 av = *(const float4*)(as_ + (size_t)s * 4);
      float e0 = av.x + adv.x; e0 = (e0 > 0.f) ? e0 : NEG * e0;
      float e1 = av.y + adv.y; e1 = (e1 > 0.f) ? e1 : NEG * e1;
      float e2 = av.z + adv.z; e2 = (e2 > 0.f) ? e2 : NEG * e2;
      float e3 = av.w + adv.w; e3 = (e3 > 0.f) ? e3 : NEG * e3;
      x0 = __expf(fminf(e0, 60.f));
      x1 = __expf(fminf(e1, 60.f));
      x2 = __expf(fminf(e2, 60.f));
      x3 = __expf(fminf(e3, 60.f));
    }
    float s0 = x0, s1 = x1, s2 = x2, s3 = x3;
#pragma unroll
    for (int o = 32; o; o >>= 1) {
      s0 += __shfl_xor(s0, o, 64);
      s1 += __shfl_xor(s1, o, 64);
      s2 += __shfl_xor(s2, o, 64);
      s3 += __shfl_xor(s3, o, 64);
    }
    unsigned w01 = pack_h2(x0 / (s0 + 1e-16f), x1 / (s1 + 1e-16f));
    unsigned w23 = pack_h2(x2 / (s2 + 1e-16f), x3 / (s3 + 1e-16f));
    __half2 acc01 = __floats2half2_rn(0.f, 0.f);
    __half2 acc23 = acc01;
#pragma unroll 4
    for (int j = 0; j < deg; ++j) {
      int oj = __builtin_amdgcn_readlane(off, j) + lane;
      unsigned W01 = __builtin_amdgcn_readlane(w01, j);
      unsigned W23 = __builtin_amdgcn_readlane(w23, j);
      __half2 hv = __half2half2(h[oj]);
      acc01 = __hfma2(hv, uas_h2(W01), acc01);
      acc23 = __hfma2(hv, uas_h2(W23), acc23);
    }
    *(__half2*)&Mrow[lane * 4] = acc01;
    *(__half2*)&Mrow[lane * 4 + 2] = acc23;
    return;
  }
  float m0 = -1e30f, m1 = -1e30f, m2 = -1e30f, m3 = -1e30f;
  for (int j = lane; j < deg; j += 64) {
    int s = col[r0 + j];
    float4 av = *(const float4*)(as_ + (size_t)s * 4);
    float e0 = av.x + adv.x; e0 = (e0 > 0.f) ? e0 : NEG * e0; m0 = fmaxf(m0, e0);
    float e1 = av.y + adv.y; e1 = (e1 > 0.f) ? e1 : NEG * e1; m1 = fmaxf(m1, e1);
    float e2 = av.z + adv.z; e2 = (e2 > 0.f) ? e2 : NEG * e2; m2 = fmaxf(m2, e2);
    float e3 = av.w + adv.w; e3 = (e3 > 0.f) ? e3 : NEG * e3; m3 = fmaxf(m3, e3);
  }
#pragma unroll
  for (int o = 32; o; o >>= 1) {
    m0 = fmaxf(m0, __shfl_xor(m0, o, 64));
    m1 = fmaxf(m1, __shfl_xor(m1, o, 64));
    m2 = fmaxf(m2, __shfl_xor(m2, o, 64));
    m3 = fmaxf(m3, __shfl_xor(m3, o, 64));
  }
  float s0 = 0.f, s1 = 0.f, s2 = 0.f, s3 = 0.f;
  for (int j = lane; j < deg; j += 64) {
    int s = col[r0 + j];
    float4 av = *(const float4*)(as_ + (size_t)s * 4);
    float e0 = av.x + adv.x; e0 = (e0 > 0.f) ? e0 : NEG * e0; s0 += __expf(e0 - m0);
    float e1 = av.y + adv.y; e1 = (e1 > 0.f) ? e1 : NEG * e1; s1 += __expf(e1 - m1);
    float e2 = av.z + adv.z; e2 = (e2 > 0.f) ? e2 : NEG * e2; s2 += __expf(e2 - m2);
    float e3 = av.w + adv.w; e3 = (e3 > 0.f) ? e3 : NEG * e3; s3 += __expf(e3 - m3);
  }
#pragma unroll
  for (int o = 32; o; o >>= 1) {
    s0 += __shfl_xor(s0, o, 64);
    s1 += __shfl_xor(s1, o, 64);
    s2 += __shfl_xor(s2, o, 64);
    s3 += __shfl_xor(s3, o, 64);
  }
  float i0 = 1.f / (s0 + 1e-16f), i1 = 1.f / (s1 + 1e-16f);
  float i2 = 1.f / (s2 + 1e-16f), i3 = 1.f / (s3 + 1e-16f);
  float a0 = 0.f, a1 = 0.f, a2 = 0.f, a3 = 0.f;
  for (int j = 0; j < deg; ++j) {
    int s = col[r0 + j];
    float4 av = *(const float4*)(as_ + (size_t)s * 4);
    float e0 = av.x + adv.x; e0 = (e0 > 0.f) ? e0 : NEG * e0;
    float e1 = av.y + adv.y; e1 = (e1 > 0.f) ? e1 : NEG * e1;
    float e2 = av.z + adv.z; e2 = (e2 > 0.f) ? e2 : NEG * e2;
    float e3 = av.w + adv.w; e3 = (e3 > 0.f) ? e3 : NEG * e3;
    float hv = __half2float(h[(s << 6) + lane]);
    a0 = fmaf(__expf(e0 - m0) * i0, hv, a0);
    a1 = fmaf(__expf(e1 - m1) * i1, hv, a1);
    a2 = fmaf(__expf(e2 - m2) * i2, hv, a2);
    a3 = fmaf(__expf(e3 - m3) * i3, hv, a3);
  }
  *(__half2*)&Mrow[lane * 4] = __floats2half2_rn(a0, a1);
  *(__half2*)&Mrow[lane * 4 + 2] = __floats2half2_rn(a2, a3);
}

// ---------------- one pair (serial path; handles slow cases) ----------------
__device__ __forceinline__ void gat_pair(
    int pr, int lane, int half, int l5, int N,
    const __half* __restrict__ h, const float* __restrict__ as_,
    const float* __restrict__ ad_, const int* __restrict__ rowptr,
    const int* __restrict__ col, __half* __restrict__ Mt) {
  int n0 = pr * 2;
  int n1 = min(n0 + 1, N - 1);
  int mynode = half ? n1 : n0;
  int r0 = rowptr[mynode];
  int dg = rowptr[mynode + 1] - r0;
  int dgA = __builtin_amdgcn_readlane(dg, 0);
  int dgB = __builtin_amdgcn_readlane(dg, 32);

  if (dgA <= 32 && dgB <= 32) {
    float4 adv = *(const float4*)(ad_ + (size_t)mynode * 4);
    int off = 0;
    float x0 = 0.f, x1 = 0.f, x2 = 0.f, x3 = 0.f;
    if (l5 < dg) {
      int s = col[r0 + l5];
      off = s << 6;
      float4 av = *(const float4*)(as_ + (size_t)s * 4);
      float e0 = av.x + adv.x; e0 = (e0 > 0.f) ? e0 : NEG * e0;
      float e1 = av.y + adv.y; e1 = (e1 > 0.f) ? e1 : NEG * e1;
      float e2 = av.z + adv.z; e2 = (e2 > 0.f) ? e2 : NEG * e2;
      float e3 = av.w + adv.w; e3 = (e3 > 0.f) ? e3 : NEG * e3;
      x0 = __expf(fminf(e0, 60.f));
      x1 = __expf(fminf(e1, 60.f));
      x2 = __expf(fminf(e2, 60.f));
      x3 = __expf(fminf(e3, 60.f));
    }
    float s0 = x0, s1 = x1, s2 = x2, s3 = x3;
#pragma unroll
    for (int o = 16; o; o >>= 1) {
      s0 += __shfl_xor(s0, o, 64);
      s1 += __shfl_xor(s1, o, 64);
      s2 += __shfl_xor(s2, o, 64);
      s3 += __shfl_xor(s3, o, 64);
    }
    unsigned w01 = pack_h2(x0 / (s0 + 1e-16f), x1 / (s1 + 1e-16f));
    unsigned w23 = pack_h2(x2 / (s2 + 1e-16f), x3 / (s3 + 1e-16f));

    int g = l5 >> 4, li = l5 & 15;
    const uint2* h4p = (const uint2*)h;
    __half2 z = __floats2half2_rn(0.f, 0.f);
    __half2 a0_01 = z, a0_23 = z, a1_01 = z, a1_23 = z;
    __half2 a2_01 = z, a2_23 = z, a3_01 = z, a3_23 = z;
    int mdeg = max(dgA, dgB);
    int baddr = half << 7;
#pragma unroll 2
    for (int j = 0; j < mdeg; j += 2) {
      int addr = baddr + (j + g) * 4;
      int oj = __builtin_amdgcn_ds_bpermute(addr, off);
      unsigned W01 = (unsigned)__builtin_amdgcn_ds_bpermute(addr, (int)w01);
      unsigned W23 = (unsigned)__builtin_amdgcn_ds_bpermute(addr, (int)w23);
      uint2 hv = h4p[(oj >> 2) + li];
      __half2 ha = uas_h2(hv.x), hb = uas_h2(hv.y);
      __half2 wA = uas_h2(W01), wB = uas_h2(W23);
      __half2 c0 = __low2half2(ha), c1 = __high2half2(ha);
      __half2 c2 = __low2half2(hb), c3 = __high2half2(hb);
      a0_01 = __hfma2(c0, wA, a0_01); a0_23 = __hfma2(c0, wB, a0_23);
      a1_01 = __hfma2(c1, wA, a1_01); a1_23 = __hfma2(c1, wB, a1_23);
      a2_01 = __hfma2(c2, wA, a2_01); a2_23 = __hfma2(c2, wB, a2_23);
      a3_01 = __hfma2(c3, wA, a3_01); a3_23 = __hfma2(c3, wB, a3_23);
    }
    a0_01 = xor16_add(a0_01); a0_23 = xor16_add(a0_23);
    a1_01 = xor16_add(a1_01); a1_23 = xor16_add(a1_23);
    a2_01 = xor16_add(a2_01); a2_23 = xor16_add(a2_23);
    a3_01 = xor16_add(a3_01); a3_23 = xor16_add(a3_23);
    if (g == 0) {
      __half* row = &Mt[(mynode & 15) * 264 + li * 16];
      uint4 st1, st2;
      st1.x = h2_as_u(a0_01); st1.y = h2_as_u(a0_23);
      st1.z = h2_as_u(a1_01); st1.w = h2_as_u(a1_23);
      st2.x = h2_as_u(a2_01); st2.y = h2_as_u(a2_23);
      st2.z = h2_as_u(a3_01); st2.w = h2_as_u(a3_23);
      *(uint4*)&row[0] = st1;
      *(uint4*)&row[8] = st2;
    }
  } else {
    gat_one_node(n0, lane, h, as_, ad_, rowptr, col, &Mt[(n0 & 15) * 264]);
    if (n1 != n0) gat_one_node(n1, lane, h, as_, ad_, rowptr, col, &Mt[(n1 & 15) * 264]);
  }
}

// ---------------- fused GAT layer: 512 threads, 8 waves x 1 pair (2x TLP for the gather) ----------------
template <bool FIN>
__global__ __launch_bounds__(512) void k_gatf(
    const __half* __restrict__ h, const float* __restrict__ as_,
    const float* __restrict__ ad_, const int* __restrict__ rowptr,
    const int* __restrict__ col, const __half* __restrict__ Wcat,
    const float* __restrict__ bg, const __half* __restrict__ Wn,
    const float* __restrict__ asrc, const float* __restrict__ adst,
    __half* __restrict__ hout, float* __restrict__ nas, float* __restrict__ nad,
    const int* __restrict__ batchv, float* __restrict__ gsums,
    int N) {
  __shared__ __half Mt[16 * 264];
  __shared__ __half O[16 * 72];
  int tid = threadIdx.x;
  int lane = tid & 63, wv = tid >> 6;   // wv in [0,8)
  int tile = blockIdx.x;
  int half = lane >> 5, l5 = lane & 31;
  int npairs = (N + 1) >> 1;

  // ---- phase 1: ONE pair per wave (8 pairs per tile); EB aliased into this pair's 2 Mt rows ----
  int pr = tile * 8 + wv;
  if (pr < npairs) {
    int n0 = pr * 2;
    int n1 = min(n0 + 1, N - 1);
    int mynode = half ? n1 : n0;
    int r0 = rowptr[mynode];
    int dg = rowptr[mynode + 1] - r0;
    int dgA = __builtin_amdgcn_readlane(dg, 0);
    int dgB = __builtin_amdgcn_readlane(dg, 32);

    if (dgA <= 32 && dgB <= 32) {
      float4 adv = *(const float4*)(ad_ + (size_t)mynode * 4);
      int off = 0;
      float x0 = 0.f, x1 = 0.f, x2 = 0.f, x3 = 0.f;
      if (l5 < dg) {
        int s = col[r0 + l5];
        off = s << 6;
        float4 av = *(const float4*)(as_ + (size_t)s * 4);
        float e0 = av.x + adv.x; e0 = (e0 > 0.f) ? e0 : NEG * e0;
        float e1 = av.y + adv.y; e1 = (e1 > 0.f) ? e1 : NEG * e1;
        float e2 = av.z + adv.z; e2 = (e2 > 0.f) ? e2 : NEG * e2;
        float e3 = av.w + adv.w; e3 = (e3 > 0.f) ? e3 : NEG * e3;
        x0 = __expf(fminf(e0, 60.f));
        x1 = __expf(fminf(e1, 60.f));
        x2 = __expf(fminf(e2, 60.f));
        x3 = __expf(fminf(e3, 60.f));
      }
      float s0 = x0, s1 = x1, s2 = x2, s3 = x3;
#pragma unroll
      for (int o = 16; o; o >>= 1) {
        s0 += __shfl_xor(s0, o, 64);
        s1 += __shfl_xor(s1, o, 64);
        s2 += __shfl_xor(s2, o, 64);
        s3 += __shfl_xor(s3, o, 64);
      }
      unsigned w01 = pack_h2(x0 / (s0 + 1e-16f), x1 / (s1 + 1e-16f));
      unsigned w23 = pack_h2(x2 / (s2 + 1e-16f), x3 / (s3 + 1e-16f));

      // per-wave EB region = this pair's 2 Mt rows (528 halves = 1056B >= 64 recs x 16B)
      uint4* EB = (uint4*)&Mt[wv * 528];
      EB[half * 32 + l5] = make_uint4((unsigned)off, w01, w23, 0u);

      int mdeg = max(dgA, dgB);
      int g = l5 >> 4, li = l5 & 15;
      int eH = half * 32;
      const uint2* h4p = (const uint2*)h;
      __half2 z = __floats2half2_rn(0.f, 0.f);
      __half2 pa0 = z, pa1 = z, pa2 = z, pa3 = z, pa4 = z, pa5 = z, pa6 = z, pa7 = z;
      __half2 qa0 = z, qa1 = z, qa2 = z, qa3 = z, qa4 = z, qa5 = z, qa6 = z, qa7 = z;
      // two independent streams (j+g, j+2+g): chain length mdeg/4, MLP 2.
      // max index = 4*floor((mdeg-1)/4)+3 <= 31 for mdeg <= 32; over-reads hit zero records.
#pragma unroll 2
      for (int j = 0; j < mdeg; j += 4) {
        uint4 ra = EB[eH + j + g];
        uint4 rb = EB[eH + j + 2 + g];
        uint2 hva = h4p[((int)ra.x >> 2) + li];
        uint2 hvb = h4p[((int)rb.x >> 2) + li];
        FMA_REC(hva, ra.y, ra.z, pa0, pa1, pa2, pa3, pa4, pa5, pa6, pa7);
        FMA_REC(hvb, rb.y, rb.z, qa0, qa1, qa2, qa3, qa4, qa5, qa6, qa7);
      }
      pa0 = __hadd2(pa0, qa0); pa1 = __hadd2(pa1, qa1);
      pa2 = __hadd2(pa2, qa2); pa3 = __hadd2(pa3, qa3);
      pa4 = __hadd2(pa4, qa4); pa5 = __hadd2(pa5, qa5);
      pa6 = __hadd2(pa6, qa6); pa7 = __hadd2(pa7, qa7);
      pa0 = xor16_add(pa0); pa1 = xor16_add(pa1); pa2 = xor16_add(pa2); pa3 = xor16_add(pa3);
      pa4 = xor16_add(pa4); pa5 = xor16_add(pa5); pa6 = xor16_add(pa6); pa7 = xor16_add(pa7);
      if (g == 0) {
        __half* row = &Mt[(mynode & 15) * 264 + li * 16];
        uint4 s1v, s2v;
        s1v.x = h2_as_u(pa0); s1v.y = h2_as_u(pa1); s1v.z = h2_as_u(pa2); s1v.w = h2_as_u(pa3);
        s2v.x = h2_as_u(pa4); s2v.y = h2_as_u(pa5); s2v.z = h2_as_u(pa6); s2v.w = h2_as_u(pa7);
        *(uint4*)&row[0] = s1v;
        *(uint4*)&row[8] = s2v;
      }
    } else {
      gat_pair(pr, lane, half, l5, N, h, as_, ad_, rowptr, col, Mt);
    }
  }
  __syncthreads();

  // ---- phase 2: head-mean GEMM on waves 0-3 (+ next-layer attn scalars, or LDS-staged pool) ----
  int quad = lane >> 4, n16 = lane & 15;
  int ch1 = wv * 16 + n16;
  if (tid < 256) {
    const f16x8* WC = (const f16x8*)Wcat;
    float bias1 = bg[ch1];
    f32x4 c1 = {0.f, 0.f, 0.f, 0.f};
#pragma unroll
    for (int i = 0; i < 8; ++i) {
      f16x8 a = *(const f16x8*)&Mt[n16 * 264 + (i * 4 + quad) * 8];
      c1 = __builtin_amdgcn_mfma_f32_16x16x32_f16(a, WC[ch1 * 32 + i * 4 + quad], c1, 0, 0, 0);
    }
#pragma unroll
    for (int r = 0; r < 4; ++r) {
      float v = fmaxf(c1[r] + bias1, 0.f);
      O[(quad * 4 + r) * 72 + ch1] = __float2half(v);
    }
  }
  __syncthreads();

  if (FIN) {
    // LDS-staged mean pool: 64 threads, one channel each
    if (tid < 64) {
      float* cnt_ = gsums + GCNT * HID;
      int c = tid;
      int nmax = min(16, N - tile * 16);
      int curg = -1;
      float acc = 0.f;
      int cacc = 0;
      for (int i = 0; i < nmax; ++i) {
        int gph = batchv[tile * 16 + i];
        float v = __half2float(O[i * 72 + c]);
        if (gph != curg) {
          if (curg >= 0) {
            atomicAdd(&gsums[curg * HID + c], acc);
            if (c == 0) atomicAdd(&cnt_[curg], (float)cacc);
          }
          curg = gph;
          acc = 0.f;
          cacc = 0;
        }
        acc += v;
        ++cacc;
      }
      if (curg >= 0) {
        atomicAdd(&gsums[curg * HID + c], acc);
        if (c == 0) atomicAdd(&cnt_[curg], (float)cacc);
      }
    }
    return;
  }

  if (tid < 256) {
    {
      int nd = tid >> 4, c0 = (tid & 15) * 4;
      int node = tile * 16 + nd;
      if (node < N) {
        uint2 v = *(const uint2*)&O[nd * 72 + c0];
        *(uint2*)&hout[(size_t)node * 64 + c0] = v;
      }
    }
    const f16x8* WN = (const f16x8*)Wn;
    f16x8 a0 = *(const f16x8*)&O[n16 * 72 + quad * 8];
    f16x8 a1 = *(const f16x8*)&O[n16 * 72 + 32 + quad * 8];
    f32x4 accs[4];
#pragma unroll
    for (int nt = 0; nt < 4; ++nt) {
      int ch = wv * 64 + nt * 16 + n16;
      f32x4 zz = {0.f, 0.f, 0.f, 0.f};
      zz = __builtin_amdgcn_mfma_f32_16x16x32_f16(a0, WN[ch * 8 + quad], zz, 0, 0, 0);
      zz = __builtin_amdgcn_mfma_f32_16x16x32_f16(a1, WN[ch * 8 + 4 + quad], zz, 0, 0, 0);
      accs[nt] = zz;
    }
#pragma unroll
    for (int r = 0; r < 4; ++r) {
      float vs = 0.f, vd = 0.f;
#pragma unroll
      for (int nt = 0; nt < 4; ++nt) {
        int ch = wv * 64 + nt * 16 + n16;
        vs = fmaf(accs[nt][r], asrc[ch], vs);
        vd = fmaf(accs[nt][r], adst[ch], vd);
      }
#pragma unroll
      for (int o = 8; o; o >>= 1) {
        vs += __shfl_xor(vs, o, 64);
        vd += __shfl_xor(vd, o, 64);
      }
      int node = tile * 16 + quad * 4 + r;
      if (n16 == 0 && node < N) {
        nas[(size_t)node * 4 + wv] = vs;
        nad[(size_t)node * 4 + wv] = vd;
      }
    }
  }
}

// ---------------- readout ----------------
__global__ void k_out(const float* __restrict__ sums, const float* __restrict__ cnt,
                      const float* __restrict__ Wout, const float* __restrict__ bout,
                      float* __restrict__ out) {
  int g = blockIdx.x, lane = threadIdx.x;
  float cg = fmaxf(cnt[g], 1.f);
  float v = (sums[g * HID + lane] / cg) * Wout[lane];
#pragma unroll
  for (int o = 32; o; o >>= 1) v += __shfl_xor(v, o, 64);
  if (lane == 0) out[g] = 1.f / (1.f + __expf(-v));
}

extern "C" void kernel_launch(void* const* d_in, const int* in_sizes, int n_in,
                              void* d_out, int out_size, void* d_ws, size_t ws_size,
                              hipStream_t stream) {
  const float* x    = (const float*)d_in[0];
  const int*   ei   = (const int*)d_in[1];
  const int*   batch= (const int*)d_in[2];
  const float* Win  = (const float*)d_in[3];
  const float* bin  = (const float*)d_in[4];
  const float* Wout = (const float*)d_in[5];
  const float* bout = (const float*)d_in[6];
  const float* Wl[3]    = {(const float*)d_in[7],  (const float*)d_in[11], (const float*)d_in[15]};
  const float* asrcl[3] = {(const float*)d_in[8],  (const float*)d_in[12], (const float*)d_in[16]};
  const float* adstl[3] = {(const float*)d_in[9],  (const float*)d_in[13], (const float*)d_in[17]};
  const float* bgl[3]   = {(const float*)d_in[10], (const float*)d_in[14], (const float*)d_in[18]};

  int N = in_sizes[2];       // 50000
  int E = in_sizes[1] / 2;   // 800000
  int EE = E + N;

  char* p = (char*)d_ws;
  auto alloc = [&](size_t bytes) {
    char* r = p;
    p += (bytes + 255) & ~(size_t)255;
    return r;
  };
  int*      rowptr = (int*)alloc((size_t)(N + 1) * 4);
  int*      col    = (int*)alloc((size_t)EE * 4);
  unsigned* tmp    = (unsigned*)alloc((size_t)NBUCK * BSLOT * 4);
  int*      bcur   = (int*)alloc((size_t)NBUCK * BSTRIDE * 4);
  float*    vb     = (float*)alloc(128 * 4);
  float*    c8     = (float*)alloc(8 * 4);
  __half*   hhA    = (__half*)alloc((size_t)N * HID * 2);
  __half*   hhB    = (__half*)alloc((size_t)N * HID * 2);
  float*    asA    = (float*)alloc((size_t)N * HEADS * 4);
  float*    adA    = (float*)alloc((size_t)N * HEADS * 4);
  float*    asB    = (float*)alloc((size_t)N * HEADS * 4);
  float*    adB    = (float*)alloc((size_t)N * HEADS * 4);
  __half*   Wh3    = (__half*)alloc(3 * 16384 * 2);
  __half*   Wcat3  = (__half*)alloc(3 * 16384 * 2);
  float*    sums   = (float*)alloc((size_t)(GCNT * HID + GCNT) * 4);
  float*    cnt    = sums + GCNT * HID;

  int tiles = (N + 15) / 16;
  int BUK = (EE + SCHUNK - 1) / SCHUNK;
  int initB = 401 + (N + 63) / 64;   // weight-prep 384 + sums 17 + inproj (64 nodes/block)

  k_pre<<<2, 256, 0, stream>>>(Wl[0], asrcl[0], adstl[0], Win, bin, bcur, vb, c8);

  k_binit<<<BUK + initB, 256, 0, stream>>>(ei, bcur, tmp, E, N,
                                           x, Win, bin, Wl[0], Wl[1], Wl[2],
                                           Wh3, Wcat3, sums, vb, c8, asA, adA, hhA, BUK);

  k_bsort<<<NBUCK, 256, 0, stream>>>(tmp, bcur, rowptr, col, N);

  k_gatf<false><<<tiles, 512, 0, stream>>>(hhA, asA, adA, rowptr, col,
                                           Wcat3, bgl[0], Wh3 + 16384, asrcl[1], adstl[1],
                                           hhB, asB, adB, nullptr, nullptr, N);
  k_gatf<false><<<tiles, 512, 0, stream>>>(hhB, asB, adB, rowptr, col,
                                           Wcat3 + 16384, bgl[1], Wh3 + 32768, asrcl[2], adstl[2],
                                           hhA, asA, adA, nullptr, nullptr, N);
  k_gatf<true><<<tiles, 512, 0, stream>>>(hhA, asA, adA, rowptr, col,
                                          Wcat3 + 32768, bgl[2], nullptr, nullptr, nullptr,
                                          nullptr, nullptr, nullptr, batch, sums, N);

  k_out<<<GCNT, 64, 0, stream>>>(sums, cnt, Wout, bout, (float*)d_out);
}

// Round 11
// 284.616 us; speedup vs baseline: 1.2839x; 1.0157x over previous
//
#include <hip/hip_runtime.h>
#include <hip/hip_bf16.h>
#include <hip/hip_fp16.h>

#define HID 64
#define HEADS 4
#define GCNT 64
#define F_IN 16
#define NEG 0.2f
#define NBUCK 256
#define BSLOT 6144
#define SCHUNK 2048
#define BSTRIDE 16  // bcur counters padded to one per 64B line (atomic-line serialization fix)

typedef _Float16 f16x8 __attribute__((ext_vector_type(8)));
typedef float f32x4 __attribute__((ext_vector_type(4)));

__device__ __forceinline__ unsigned pack_h2(float a, float b) {
  __half2 h = __floats2half2_rn(a, b);
  union { __half2 h; unsigned u; } c;
  c.h = h;
  return c.u;
}
__device__ __forceinline__ __half2 uas_h2(unsigned u) {
  union { unsigned u; __half2 h; } c;
  c.u = u;
  return c.h;
}
__device__ __forceinline__ unsigned h2_as_u(__half2 h) {
  union { __half2 h; unsigned u; } c;
  c.h = h;
  return c.u;
}
__device__ __forceinline__ __half2 xor16_add(__half2 v) {
  unsigned u = (unsigned)__shfl_xor((int)h2_as_u(v), 16, 64);
  return __hadd2(v, uas_h2(u));
}

// one gathered h-row fragment (uint2 = 4 halfs) x edge weights (2 half2) -> 8 accum half2
#define FMA_REC(HV, W01, W23, P0, P1, P2, P3, P4, P5, P6, P7)      \
  do {                                                             \
    __half2 _ha = uas_h2((HV).x), _hb = uas_h2((HV).y);            \
    __half2 _wA = uas_h2(W01), _wB = uas_h2(W23);                  \
    __half2 _c0 = __low2half2(_ha), _c1 = __high2half2(_ha);       \
    __half2 _c2 = __low2half2(_hb), _c3 = __high2half2(_hb);       \
    P0 = __hfma2(_c0, _wA, P0); P1 = __hfma2(_c0, _wB, P1);        \
    P2 = __hfma2(_c1, _wA, P2); P3 = __hfma2(_c1, _wB, P3);        \
    P4 = __hfma2(_c2, _wA, P4); P5 = __hfma2(_c2, _wB, P5);        \
    P6 = __hfma2(_c3, _wA, P6); P7 = __hfma2(_c3, _wB, P7);        \
  } while (0)

// ---------------- pre: zero padded bucket cursors + fold layer-0 attn through Win ----------------
__global__ __launch_bounds__(256) void k_pre(
    const float* __restrict__ W0, const float* __restrict__ asrc,
    const float* __restrict__ adst, const float* __restrict__ Win,
    const float* __restrict__ bin, int* __restrict__ bcur,
    float* __restrict__ vb, float* __restrict__ c8) {
  int t = threadIdx.x;
  if (blockIdx.x == 0) {
    for (int i = t; i < NBUCK * BSTRIDE; i += 256) bcur[i] = 0;
    return;
  }
  __shared__ float vaL[512];
#pragma unroll
  for (int it = 0; it < 2; ++it) {
    int idx = t + it * 256;
    int q = idx >> 6, j = idx & 63;
    const float* a = (q < 4) ? asrc : adst;
    int h = q & 3;
    float s = 0.f;
    for (int c = 0; c < 64; ++c) s += a[h * 64 + c] * W0[(h * 64 + c) * 64 + j];
    vaL[idx] = s;
  }
  __syncthreads();
  if (t < 128) {
    int q = t >> 4, k = t & 15;
    float s = 0.f;
    for (int j = 0; j < 64; ++j) s += vaL[q * 64 + j] * Win[j * F_IN + k];
    vb[t] = s;
  } else if (t < 136) {
    int q = t - 128;
    float s = 0.f;
    for (int j = 0; j < 64; ++j) s += vaL[q * 64 + j] * bin[j];
    c8[q] = s;
  }
}

// ---------------- fused: CSR pass 1 (bucket, local-sorted write-out) + weight prep + inproj ----------------
__global__ __launch_bounds__(256) void k_binit(
    const int* __restrict__ ei, int* __restrict__ bcur,
    unsigned* __restrict__ tmp, int E, int N,
    const float* __restrict__ x, const float* __restrict__ Win,
    const float* __restrict__ bin,
    const float* __restrict__ W0, const float* __restrict__ W1,
    const float* __restrict__ W2,
    __half* __restrict__ Wh3, __half* __restrict__ Wcat3,
    float* __restrict__ sums, const float* __restrict__ vb,
    const float* __restrict__ c8,
    float* __restrict__ as_, float* __restrict__ ad_,
    __half* __restrict__ hh, int BUK) {
  int t = threadIdx.x;
  if (blockIdx.x < BUK) {
    // ---- bucket path: count -> local bucket-sort in LDS -> coalesced burst write-out ----
    __shared__ int hist[NBUCK];
    __shared__ int base[NBUCK];
    __shared__ int loff[NBUCK];
    __shared__ unsigned placed[SCHUNK];
    int start = blockIdx.x * SCHUNK;
    int end = min(start + SCHUNK, E + N);
    int cntr = end - start;
    hist[t] = 0;
    __syncthreads();
    unsigned val[8];
    int rank[8];
    bool ok[8];
#pragma unroll
    for (int k = 0; k < 8; ++k) {
      int i = start + t + k * 256;
      ok[k] = i < end;
      if (ok[k]) {
        int s, d;
        if (i < E) {
          s = ei[i];
          d = ei[E + i];
        } else {
          s = d = i - E;
        }
        val[k] = ((unsigned)d << 16) | (unsigned)s;
        rank[k] = atomicAdd(&hist[d >> 8], 1);
      }
    }
    __syncthreads();
    int h = hist[t];
    // padded counters: one atomic per 64B line -> no same-line serialization
    base[t] = h ? atomicAdd(&bcur[t * BSTRIDE], h) : 0;
    loff[t] = h;
    __syncthreads();
    for (int o = 1; o < 256; o <<= 1) {
      int xg = (t >= o) ? loff[t - o] : 0;
      __syncthreads();
      loff[t] += xg;
      __syncthreads();
    }
    int ex = loff[t] - h;   // exclusive scan
    __syncthreads();
    loff[t] = ex;
    __syncthreads();
    // place records bucket-sorted in LDS
#pragma unroll
    for (int k = 0; k < 8; ++k) {
      if (ok[k]) {
        int bk = (int)(val[k] >> 24);
        placed[loff[bk] + rank[k]] = val[k];
      }
    }
    __syncthreads();
    // write-out: consecutive threads cover contiguous bucket runs -> burst stores
    for (int j = t; j < cntr; j += 256) {
      unsigned v = placed[j];
      int bk = (int)(v >> 24);
      int idx = base[bk] + (j - loff[bk]);
      if (idx < BSLOT) tmp[(size_t)bk * BSLOT + idx] = v;
    }
    return;
  }
  // ---- weight prep / zero path ----
  int b = blockIdx.x - BUK;
  if (b < 384) {
    int i = b * 256 + t;
    if (i < 49152) {
      const float* W = (i < 16384) ? W0 : (i < 32768) ? W1 : W2;
      Wh3[i] = __float2half(W[i & 16383]);
    } else {
      int j = i - 49152;
      int l = j >> 14;
      int r = j & 16383;
      int c = r >> 8;
      int k256 = r & 255;
      int h = k256 & 3, kk = k256 >> 2;
      const float* W = (l == 0) ? W0 : (l == 1) ? W1 : W2;
      Wcat3[j] = __float2half(0.25f * W[(h * 64 + c) * 64 + kk]);
    }
    return;
  }
  if (b < 401) {
    int i = (b - 384) * 256 + t;
    if (i < GCNT * HID + GCNT) sums[i] = 0.f;
    return;
  }
  // ---- inproj path: 64 nodes/block, 4 threads/node, LDS-staged weights ----
  {
    __shared__ float Ws[1024];   // Win 64x16 row-major (j*16+k)
    __shared__ float vbs[128];
    __shared__ float bins[64];
    __shared__ float c8s[8];
    for (int i = t; i < 1024; i += 256) Ws[i] = Win[i];
    if (t < 128) vbs[t] = vb[t];
    if (t < 64) bins[t] = bin[t];
    if (t < 8) c8s[t] = c8[t];
    __syncthreads();
    int b2 = b - 401;
    int n = b2 * 64 + (t >> 2);
    int p = t & 3;
    if (n >= N) return;
    const float4* xr4 = (const float4*)(x + (size_t)n * F_IN);
    float4 a0 = xr4[0], a1 = xr4[1], a2 = xr4[2], a3 = xr4[3];
    float xv[16] = {a0.x, a0.y, a0.z, a0.w, a1.x, a1.y, a1.z, a1.w,
                    a2.x, a2.y, a2.z, a2.w, a3.x, a3.y, a3.z, a3.w};
    unsigned hv[8];
#pragma unroll
    for (int jj = 0; jj < 16; jj += 2) {
      int j = p * 16 + jj;
      float acc0 = bins[j], acc1 = bins[j + 1];
#pragma unroll
      for (int k = 0; k < 16; ++k) {
        acc0 = fmaf(xv[k], Ws[j * 16 + k], acc0);
        acc1 = fmaf(xv[k], Ws[(j + 1) * 16 + k], acc1);
      }
      hv[jj >> 1] = pack_h2(acc0, acc1);
    }
    uint4* dst = (uint4*)(hh + (size_t)n * 64 + p * 16);
    dst[0] = make_uint4(hv[0], hv[1], hv[2], hv[3]);
    dst[1] = make_uint4(hv[4], hv[5], hv[6], hv[7]);
    if (p == 0) {
      float sq[8];
#pragma unroll
      for (int q = 0; q < 8; ++q) {
        float s = c8s[q];
#pragma unroll
        for (int k = 0; k < 16; ++k) s = fmaf(xv[k], vbs[q * 16 + k], s);
        sq[q] = s;
      }
      *(float4*)(as_ + (size_t)n * 4) = make_float4(sq[0], sq[1], sq[2], sq[3]);
      *(float4*)(ad_ + (size_t)n * 4) = make_float4(sq[4], sq[5], sq[6], sq[7]);
    }
  }
}

// ---------------- CSR pass 2: per-bucket counting sort (LDS-staged records) -> rowptr + col ----------------
__global__ __launch_bounds__(256) void k_bsort(
    const unsigned* __restrict__ tmp, const int* __restrict__ bcur,
    int* __restrict__ rowptr, int* __restrict__ col, int N) {
  __shared__ int s[NBUCK];
  __shared__ int hist[NBUCK];
  __shared__ int pref[NBUCK];
  __shared__ unsigned recs[BSLOT];
  int b = blockIdx.x, t = threadIdx.x;
  int c = min(bcur[t * BSTRIDE], BSLOT);
  s[t] = c;
  __syncthreads();
  for (int o = 1; o < 256; o <<= 1) {
    int x = (t >= o) ? s[t - o] : 0;
    __syncthreads();
    s[t] += x;
    __syncthreads();
  }
  int base = (b == 0) ? 0 : s[b - 1];
  int total = s[255];
  int cntb = min(bcur[b * BSTRIDE], BSLOT);
  hist[t] = 0;
  __syncthreads();
  // stage bucket records in LDS + histogram in one pass
  for (int j = t; j < cntb; j += 256) {
    unsigned e = tmp[(size_t)b * BSLOT + j];
    recs[j] = e;
    atomicAdd(&hist[(e >> 16) & 255], 1);
  }
  __syncthreads();
  int v = hist[t];
  pref[t] = v;
  __syncthreads();
  for (int o = 1; o < 256; o <<= 1) {
    int x = (t >= o) ? pref[t - o] : 0;
    __syncthreads();
    pref[t] += x;
    __syncthreads();
  }
  pref[t] -= v;
  __syncthreads();
  int node = b * 256 + t;
  if (node < N) rowptr[node] = base + pref[t];
  if (b == 255 && t == 255) rowptr[N] = total;
  hist[t] = 0;
  __syncthreads();
  for (int j = t; j < cntb; j += 256) {
    unsigned e = recs[j];
    int d8 = (int)((e >> 16) & 255);
    int r = atomicAdd(&hist[d8], 1);
    col[base + pref[d8] + r] = (int)(e & 0xffffu);
  }
}

// ---------------- single-node helper (any deg): writes one M row to LDS ----------------
__device__ __forceinline__ void gat_one_node(
    int node, int lane, const __half* __restrict__ h, const float* __restrict__ as_,
    const float* __restrict__ ad_, const int* __restrict__ rowptr,
    const int* __restrict__ col, __half* __restrict__ Mrow) {
  int r0 = rowptr[node];
  int deg = rowptr[node + 1] - r0;
  float4 adv = *(const float4*)(ad_ + (size_t)node * 4);

  if (deg <= 64) {
    int off = 0;
    float x0 = 0.f, x1 = 0.f, x2 = 0.f, x3 = 0.f;
    if (lane < deg) {
      int s = col[r0 + lane];
      off = s << 6;
      float4 av = *(const float4*)(as_ + (size_t)s * 4);
      float e0 = av.x + adv.x; e0 = (e0 > 0.f) ? e0 : NEG * e0;
      float e1 = av.y + adv.y; e1 = (e1 > 0.f) ? e1 : NEG * e1;
      float e2 = av.z + adv.z; e2 = (e2 > 0.f) ? e2 : NEG * e2;
      float e3 = av.w + adv.w; e3 = (e3 > 0.f) ? e3 : NEG * e3;
      x0 = __expf(fminf(e0, 60.f));
      x1 = __expf(fminf(e1, 60.f));
      x2 = __expf(fminf(e2, 60.f));
      x3 = __expf(fminf(e3, 60.f));
    }
    float s0 = x0, s1 = x1, s2 = x2, s3 = x3;
#pragma unroll
    for (int o = 32; o; o >>= 1) {
      s0 += __shfl_xor(s0, o, 64);
      s1 += __shfl_xor(s1, o, 64);
      s2 += __shfl_xor(s2, o, 64);
      s3 += __shfl_xor(s3, o, 64);
    }
    unsigned w01 = pack_h2(x0 / (s0 + 1e-16f), x1 / (s1 + 1e-16f));
    unsigned w23 = pack_h2(x2 / (s2 + 1e-16f), x3 / (s3 + 1e-16f));
    __half2 acc01 = __floats2half2_rn(0.f, 0.f);
    __half2 acc23 = acc01;
#pragma unroll 4
    for (int j = 0; j < deg; ++j) {
      int oj = __builtin_amdgcn_readlane(off, j) + lane;
      unsigned W01 = __builtin_amdgcn_readlane(w01, j);
      unsigned W23 = __builtin_amdgcn_readlane(w23, j);
      __half2 hv = __half2half2(h[oj]);
      acc01 = __hfma2(hv, uas_h2(W01), acc01);
      acc23 = __hfma2(hv, uas_h2(W23), acc23);
    }
    *(__half2*)&Mrow[lane * 4] = acc01;
    *(__half2*)&Mrow[lane * 4 + 2] = acc23;
    return;
  }
  float m0 = -1e30f, m1 = -1e30f, m2 = -1e30f, m3 = -1e30f;
  for (int j = lane; j < deg; j += 64) {
    int s = col[r0 + j];
    float4 av = *(const float4*)(as_ + (size_t)s * 4);
    float e0 = av.x + adv.x; e0 = (e0 > 0.f) ? e0 : NEG * e0; m0 = fmaxf(m0, e0);
    float e1 = av.y + adv.y; e1 = (e1 > 0.f) ? e1 : NEG * e1; m1 = fmaxf(m1, e1);
    float e2 = av.z + adv.z; e2 = (e2 > 0.f) ? e2 : NEG * e2; m2 = fmaxf(m2, e2);
    float e3 = av.w + adv.w; e3 = (e3 > 0.f) ? e3 : NEG * e3; m3 = fmaxf(m3, e3);
  }
#pragma unroll
  for (int o = 32; o; o >>= 1) {
    m0 = fmaxf(m0, __shfl_xor(m0, o, 64));
    m1 = fmaxf(m1, __shfl_xor(m1, o, 64));
    m2 = fmaxf(m2, __shfl_xor(m2, o, 64));
    m3 = fmaxf(m3, __shfl_xor(m3, o, 64));
  }
  float s0 = 0.f, s1 = 0.f, s2 = 0.f, s3 = 0.f;
  for (int j = lane; j < deg; j += 64) {
    int s = col[r0 + j];
    float4 av = *(const float4*)(as_ + (size_t)s * 4);
    float e0 = av.x + adv.x; e0 = (e0 > 0.f) ? e0 : NEG * e0; s0 += __expf(e0 - m0);
    float e1 = av.y + adv.y; e1 = (e1 > 0.f) ? e1 : NEG * e1; s1 += __expf(e1 - m1);
    float e2 = av.z + adv.z; e2 = (e2 > 0.f) ? e2 : NEG * e2; s2 += __expf(e2 - m2);
    float e3 = av.w + adv.w; e3 = (e3 > 0.f) ? e3 : NEG * e3; s3 += __expf(e3 - m3);
  }
#pragma unroll
  for (int o = 32; o; o >>= 1) {
    s0 += __shfl_xor(s0, o, 64);
    s1 += __shfl_xor(s1, o, 64);
    s2 += __shfl_xor(s2, o, 64);
    s3 += __shfl_xor(s3, o, 64);
  }
  float i0 = 1.f / (s0 + 1e-16f), i1 = 1.f / (s1 + 1e-16f);
  float i2 = 1.f / (s2 + 1e-16f), i3 = 1.f / (s3 + 1e-16f);
  float a0 = 0.f, a1 = 0.f, a2 = 0.f, a3 = 0.f;
  for (int j = 0; j < deg; ++j) {
    int s = col[r0 + j];
    float4 av = *(const float4*)(as_ + (size_t)s * 4);
    float e0 = av.x + adv.x; e0 = (e0 > 0.f) ? e0 : NEG * e0;
    float e1 = av.y + adv.y; e1 = (e1 > 0.f) ? e1 : NEG * e1;
    float e2 = av.z + adv.z; e2 = (e2 > 0.f) ? e2 : NEG * e2;
    float e3 = av.w + adv.w; e3 = (e3 > 0.f) ? e3 : NEG * e3;
    float hv = __half2float(h[(s << 6) + lane]);
    a0 = fmaf(__expf(e0 - m0) * i0, hv, a0);
    a1 = fmaf(__expf(e1 - m1) * i1, hv, a1);
    a2 = fmaf(__expf(e2 - m2) * i2, hv, a2);
    a3 = fmaf(__expf(e3 - m3) * i3, hv, a3);
  }
  *(__half2*)&Mrow[lane * 4] = __floats2half2_rn(a0, a1);
  *(__half2*)&Mrow[lane * 4 + 2] = __floats2half2_rn(a2, a3);
}

// ---------------- one pair (serial path; handles slow cases) ----------------
__device__ __forceinline__ void gat_pair(
    int pr, int lane, int half, int l5, int N,
    const __half* __restrict__ h, const float* __restrict__ as_,
    const float* __restrict__ ad_, const int* __restrict__ rowptr,
    const int* __restrict__ col, __half* __restrict__ Mt) {
  int n0 = pr * 2;
  int n1 = min(n0 + 1, N - 1);
  int mynode = half ? n1 : n0;
  int r0 = rowptr[mynode];
  int dg = rowptr[mynode + 1] - r0;
  int dgA = __builtin_amdgcn_readlane(dg, 0);
  int dgB = __builtin_amdgcn_readlane(dg, 32);

  if (dgA <= 32 && dgB <= 32) {
    float4 adv = *(const float4*)(ad_ + (size_t)mynode * 4);
    int off = 0;
    float x0 = 0.f, x1 = 0.f, x2 = 0.f, x3 = 0.f;
    if (l5 < dg) {
      int s = col[r0 + l5];
      off = s << 6;
      float4 av = *(const float4*)(as_ + (size_t)s * 4);
      float e0 = av.x + adv.x; e0 = (e0 > 0.f) ? e0 : NEG * e0;
      float e1 = av.y + adv.y; e1 = (e1 > 0.f) ? e1 : NEG * e1;
      float e2 = av.z + adv.z; e2 = (e2 > 0.f) ? e2 : NEG * e2;
      float e3 = av.w + adv.w; e3 = (e3 > 0.f) ? e3 : NEG * e3;
      x0 = __expf(fminf(e0, 60.f));
      x1 = __expf(fminf(e1, 60.f));
      x2 = __expf(fminf(e2, 60.f));
      x3 = __expf(fminf(e3, 60.f));
    }
    float s0 = x0, s1 = x1, s2 = x2, s3 = x3;
#pragma unroll
    for (int o = 16; o; o >>= 1) {
      s0 += __shfl_xor(s0, o, 64);
      s1 += __shfl_xor(s1, o, 64);
      s2 += __shfl_xor(s2, o, 64);
      s3 += __shfl_xor(s3, o, 64);
    }
    unsigned w01 = pack_h2(x0 / (s0 + 1e-16f), x1 / (s1 + 1e-16f));
    unsigned w23 = pack_h2(x2 / (s2 + 1e-16f), x3 / (s3 + 1e-16f));

    int g = l5 >> 4, li = l5 & 15;
    const uint2* h4p = (const uint2*)h;
    __half2 z = __floats2half2_rn(0.f, 0.f);
    __half2 a0_01 = z, a0_23 = z, a1_01 = z, a1_23 = z;
    __half2 a2_01 = z, a2_23 = z, a3_01 = z, a3_23 = z;
    int mdeg = max(dgA, dgB);
    int baddr = half << 7;
#pragma unroll 2
    for (int j = 0; j < mdeg; j += 2) {
      int addr = baddr + (j + g) * 4;
      int oj = __builtin_amdgcn_ds_bpermute(addr, off);
      unsigned W01 = (unsigned)__builtin_amdgcn_ds_bpermute(addr, (int)w01);
      unsigned W23 = (unsigned)__builtin_amdgcn_ds_bpermute(addr, (int)w23);
      uint2 hv = h4p[(oj >> 2) + li];
      __half2 ha = uas_h2(hv.x), hb = uas_h2(hv.y);
      __half2 wA = uas_h2(W01), wB = uas_h2(W23);
      __half2 c0 = __low2half2(ha), c1 = __high2half2(ha);
      __half2 c2 = __low2half2(hb), c3 = __high2half2(hb);
      a0_01 = __hfma2(c0, wA, a0_01); a0_23 = __hfma2(c0, wB, a0_23);
      a1_01 = __hfma2(c1, wA, a1_01); a1_23 = __hfma2(c1, wB, a1_23);
      a2_01 = __hfma2(c2, wA, a2_01); a2_23 = __hfma2(c2, wB, a2_23);
      a3_01 = __hfma2(c3, wA, a3_01); a3_23 = __hfma2(c3, wB, a3_23);
    }
    a0_01 = xor16_add(a0_01); a0_23 = xor16_add(a0_23);
    a1_01 = xor16_add(a1_01); a1_23 = xor16_add(a1_23);
    a2_01 = xor16_add(a2_01); a2_23 = xor16_add(a2_23);
    a3_01 = xor16_add(a3_01); a3_23 = xor16_add(a3_23);
    if (g == 0) {
      __half* row = &Mt[(mynode & 15) * 264 + li * 16];
      uint4 st1, st2;
      st1.x = h2_as_u(a0_01); st1.y = h2_as_u(a0_23);
      st1.z = h2_as_u(a1_01); st1.w = h2_as_u(a1_23);
      st2.x = h2_as_u(a2_01); st2.y = h2_as_u(a2_23);
      st2.z = h2_as_u(a3_01); st2.w = h2_as_u(a3_23);
      *(uint4*)&row[0] = st1;
      *(uint4*)&row[8] = st2;
    }
  } else {
    gat_one_node(n0, lane, h, as_, ad_, rowptr, col, &Mt[(n0 & 15) * 264]);
    if (n1 != n0) gat_one_node(n1, lane, h, as_, ad_, rowptr, col, &Mt[(n1 & 15) * 264]);
  }
}

// ---------------- fused GAT layer: 512 threads, 8 waves x 1 pair ----------------
template <bool FIN>
__global__ __launch_bounds__(512) void k_gatf(
    const __half* __restrict__ h, const float* __restrict__ as_,
    const float* __restrict__ ad_, const int* __restrict__ rowptr,
    const int* __restrict__ col, const __half* __restrict__ Wcat,
    const float* __restrict__ bg, const __half* __restrict__ Wn,
    const float* __restrict__ asrc, const float* __restrict__ adst,
    __half* __restrict__ hout, float* __restrict__ nas, float* __restrict__ nad,
    const int* __restrict__ batchv, float* __restrict__ gsums,
    int N) {
  __shared__ __half Mt[16 * 264];
  __shared__ __half O[16 * 72];
  int tid = threadIdx.x;
  int lane = tid & 63, wv = tid >> 6;   // wv in [0,8)
  int tile = blockIdx.x;
  int half = lane >> 5, l5 = lane & 31;
  int npairs = (N + 1) >> 1;

  // ---- phase 1: ONE pair per wave (8 pairs per tile); EB aliased into this pair's 2 Mt rows ----
  int pr = tile * 8 + wv;
  if (pr < npairs) {
    int n0 = pr * 2;
    int n1 = min(n0 + 1, N - 1);
    int mynode = half ? n1 : n0;
    int r0 = rowptr[mynode];
    int dg = rowptr[mynode + 1] - r0;
    int dgA = __builtin_amdgcn_readlane(dg, 0);
    int dgB = __builtin_amdgcn_readlane(dg, 32);

    if (dgA <= 32 && dgB <= 32) {
      float4 adv = *(const float4*)(ad_ + (size_t)mynode * 4);
      int off = 0;
      float x0 = 0.f, x1 = 0.f, x2 = 0.f, x3 = 0.f;
      if (l5 < dg) {
        int s = col[r0 + l5];
        off = s << 6;
        float4 av = *(const float4*)(as_ + (size_t)s * 4);
        float e0 = av.x + adv.x; e0 = (e0 > 0.f) ? e0 : NEG * e0;
        float e1 = av.y + adv.y; e1 = (e1 > 0.f) ? e1 : NEG * e1;
        float e2 = av.z + adv.z; e2 = (e2 > 0.f) ? e2 : NEG * e2;
        float e3 = av.w + adv.w; e3 = (e3 > 0.f) ? e3 : NEG * e3;
        x0 = __expf(fminf(e0, 60.f));
        x1 = __expf(fminf(e1, 60.f));
        x2 = __expf(fminf(e2, 60.f));
        x3 = __expf(fminf(e3, 60.f));
      }
      float s0 = x0, s1 = x1, s2 = x2, s3 = x3;
#pragma unroll
      for (int o = 16; o; o >>= 1) {
        s0 += __shfl_xor(s0, o, 64);
        s1 += __shfl_xor(s1, o, 64);
        s2 += __shfl_xor(s2, o, 64);
        s3 += __shfl_xor(s3, o, 64);
      }
      unsigned w01 = pack_h2(x0 / (s0 + 1e-16f), x1 / (s1 + 1e-16f));
      unsigned w23 = pack_h2(x2 / (s2 + 1e-16f), x3 / (s3 + 1e-16f));

      // per-wave EB region = this pair's 2 Mt rows (528 halves = 1056B >= 64 recs x 16B)
      uint4* EB = (uint4*)&Mt[wv * 528];
      EB[half * 32 + l5] = make_uint4((unsigned)off, w01, w23, 0u);

      int mdeg = max(dgA, dgB);
      int g = l5 >> 4, li = l5 & 15;
      int eH = half * 32;
      const uint2* h4p = (const uint2*)h;
      __half2 z = __floats2half2_rn(0.f, 0.f);
      __half2 pa0 = z, pa1 = z, pa2 = z, pa3 = z, pa4 = z, pa5 = z, pa6 = z, pa7 = z;
      __half2 qa0 = z, qa1 = z, qa2 = z, qa3 = z, qa4 = z, qa5 = z, qa6 = z, qa7 = z;
#pragma unroll 2
      for (int j = 0; j < mdeg; j += 4) {
        uint4 ra = EB[eH + j + g];
        uint4 rb = EB[eH + j + 2 + g];
        uint2 hva = h4p[((int)ra.x >> 2) + li];
        uint2 hvb = h4p[((int)rb.x >> 2) + li];
        FMA_REC(hva, ra.y, ra.z, pa0, pa1, pa2, pa3, pa4, pa5, pa6, pa7);
        FMA_REC(hvb, rb.y, rb.z, qa0, qa1, qa2, qa3, qa4, qa5, qa6, qa7);
      }
      pa0 = __hadd2(pa0, qa0); pa1 = __hadd2(pa1, qa1);
      pa2 = __hadd2(pa2, qa2); pa3 = __hadd2(pa3, qa3);
      pa4 = __hadd2(pa4, qa4); pa5 = __hadd2(pa5, qa5);
      pa6 = __hadd2(pa6, qa6); pa7 = __hadd2(pa7, qa7);
      pa0 = xor16_add(pa0); pa1 = xor16_add(pa1); pa2 = xor16_add(pa2); pa3 = xor16_add(pa3);
      pa4 = xor16_add(pa4); pa5 = xor16_add(pa5); pa6 = xor16_add(pa6); pa7 = xor16_add(pa7);
      if (g == 0) {
        __half* row = &Mt[(mynode & 15) * 264 + li * 16];
        uint4 s1v, s2v;
        s1v.x = h2_as_u(pa0); s1v.y = h2_as_u(pa1); s1v.z = h2_as_u(pa2); s1v.w = h2_as_u(pa3);
        s2v.x = h2_as_u(pa4); s2v.y = h2_as_u(pa5); s2v.z = h2_as_u(pa6); s2v.w = h2_as_u(pa7);
        *(uint4*)&row[0] = s1v;
        *(uint4*)&row[8] = s2v;
      }
    } else {
      gat_pair(pr, lane, half, l5, N, h, as_, ad_, rowptr, col, Mt);
    }
  }
  __syncthreads();

  // ---- phase 2: head-mean GEMM on waves 0-3 (+ next-layer attn scalars, or LDS-staged pool) ----
  int quad = lane >> 4, n16 = lane & 15;
  int ch1 = wv * 16 + n16;
  if (tid < 256) {
    const f16x8* WC = (const f16x8*)Wcat;
    float bias1 = bg[ch1];
    f32x4 c1 = {0.f, 0.f, 0.f, 0.f};
#pragma unroll
    for (int i = 0; i < 8; ++i) {
      f16x8 a = *(const f16x8*)&Mt[n16 * 264 + (i * 4 + quad) * 8];
      c1 = __builtin_amdgcn_mfma_f32_16x16x32_f16(a, WC[ch1 * 32 + i * 4 + quad], c1, 0, 0, 0);
    }
#pragma unroll
    for (int r = 0; r < 4; ++r) {
      float v = fmaxf(c1[r] + bias1, 0.f);
      O[(quad * 4 + r) * 72 + ch1] = __float2half(v);
    }
  }
  __syncthreads();

  if (FIN) {
    // LDS-staged mean pool: 64 threads, one channel each
    if (tid < 64) {
      float* cnt_ = gsums + GCNT * HID;
      int c = tid;
      int nmax = min(16, N - tile * 16);
      int curg = -1;
      float acc = 0.f;
      int cacc = 0;
      for (int i = 0; i < nmax; ++i) {
        int gph = batchv[tile * 16 + i];
        float v = __half2float(O[i * 72 + c]);
        if (gph != curg) {
          if (curg >= 0) {
            atomicAdd(&gsums[curg * HID + c], acc);
            if (c == 0) atomicAdd(&cnt_[curg], (float)cacc);
          }
          curg = gph;
          acc = 0.f;
          cacc = 0;
        }
        acc += v;
        ++cacc;
      }
      if (curg >= 0) {
        atomicAdd(&gsums[curg * HID + c], acc);
        if (c == 0) atomicAdd(&cnt_[curg], (float)cacc);
      }
    }
    return;
  }

  if (tid < 256) {
    {
      int nd = tid >> 4, c0 = (tid & 15) * 4;
      int node = tile * 16 + nd;
      if (node < N) {
        uint2 v = *(const uint2*)&O[nd * 72 + c0];
        *(uint2*)&hout[(size_t)node * 64 + c0] = v;
      }
    }
    const f16x8* WN = (const f16x8*)Wn;
    f16x8 a0 = *(const f16x8*)&O[n16 * 72 + quad * 8];
    f16x8 a1 = *(const f16x8*)&O[n16 * 72 + 32 + quad * 8];
    f32x4 accs[4];
#pragma unroll
    for (int nt = 0; nt < 4; ++nt) {
      int ch = wv * 64 + nt * 16 + n16;
      f32x4 zz = {0.f, 0.f, 0.f, 0.f};
      zz = __builtin_amdgcn_mfma_f32_16x16x32_f16(a0, WN[ch * 8 + quad], zz, 0, 0, 0);
      zz = __builtin_amdgcn_mfma_f32_16x16x32_f16(a1, WN[ch * 8 + 4 + quad], zz, 0, 0, 0);
      accs[nt] = zz;
    }
#pragma unroll
    for (int r = 0; r < 4; ++r) {
      float vs = 0.f, vd = 0.f;
#pragma unroll
      for (int nt = 0; nt < 4; ++nt) {
        int ch = wv * 64 + nt * 16 + n16;
        vs = fmaf(accs[nt][r], asrc[ch], vs);
        vd = fmaf(accs[nt][r], adst[ch], vd);
      }
#pragma unroll
      for (int o = 8; o; o >>= 1) {
        vs += __shfl_xor(vs, o, 64);
        vd += __shfl_xor(vd, o, 64);
      }
      int node = tile * 16 + quad * 4 + r;
      if (n16 == 0 && node < N) {
        nas[(size_t)node * 4 + wv] = vs;
        nad[(size_t)node * 4 + wv] = vd;
      }
    }
  }
}

// ---------------- readout ----------------
__global__ void k_out(const float* __restrict__ sums, const float* __restrict__ cnt,
                      const float* __restrict__ Wout, const float* __restrict__ bout,
                      float* __restrict__ out) {
  int g = blockIdx.x, lane = threadIdx.x;
  float cg = fmaxf(cnt[g], 1.f);
  float v = (sums[g * HID + lane] / cg) * Wout[lane];
#pragma unroll
  for (int o = 32; o; o >>= 1) v += __shfl_xor(v, o, 64);
  if (lane == 0) out[g] = 1.f / (1.f + __expf(-v));
}

extern "C" void kernel_launch(void* const* d_in, const int* in_sizes, int n_in,
                              void* d_out, int out_size, void* d_ws, size_t ws_size,
                              hipStream_t stream) {
  const float* x    = (const float*)d_in[0];
  const int*   ei   = (const int*)d_in[1];
  const int*   batch= (const int*)d_in[2];
  const float* Win  = (const float*)d_in[3];
  const float* bin  = (const float*)d_in[4];
  const float* Wout = (const float*)d_in[5];
  const float* bout = (const float*)d_in[6];
  const float* Wl[3]    = {(const float*)d_in[7],  (const float*)d_in[11], (const float*)d_in[15]};
  const float* asrcl[3] = {(const float*)d_in[8],  (const float*)d_in[12], (const float*)d_in[16]};
  const float* adstl[3] = {(const float*)d_in[9],  (const float*)d_in[13], (const float*)d_in[17]};
  const float* bgl[3]   = {(const float*)d_in[10], (const float*)d_in[14], (const float*)d_in[18]};

  int N = in_sizes[2];       // 50000
  int E = in_sizes[1] / 2;   // 800000
  int EE = E + N;

  char* p = (char*)d_ws;
  auto alloc = [&](size_t bytes) {
    char* r = p;
    p += (bytes + 255) & ~(size_t)255;
    return r;
  };
  int*      rowptr = (int*)alloc((size_t)(N + 1) * 4);
  int*      col    = (int*)alloc((size_t)EE * 4);
  unsigned* tmp    = (unsigned*)alloc((size_t)NBUCK * BSLOT * 4);
  int*      bcur   = (int*)alloc((size_t)NBUCK * BSTRIDE * 4);
  float*    vb     = (float*)alloc(128 * 4);
  float*    c8     = (float*)alloc(8 * 4);
  __half*   hhA    = (__half*)alloc((size_t)N * HID * 2);
  __half*   hhB    = (__half*)alloc((size_t)N * HID * 2);
  float*    asA    = (float*)alloc((size_t)N * HEADS * 4);
  float*    adA    = (float*)alloc((size_t)N * HEADS * 4);
  float*    asB    = (float*)alloc((size_t)N * HEADS * 4);
  float*    adB    = (float*)alloc((size_t)N * HEADS * 4);
  __half*   Wh3    = (__half*)alloc(3 * 16384 * 2);
  __half*   Wcat3  = (__half*)alloc(3 * 16384 * 2);
  float*    sums   = (float*)alloc((size_t)(GCNT * HID + GCNT) * 4);
  float*    cnt    = sums + GCNT * HID;

  int tiles = (N + 15) / 16;
  int BUK = (EE + SCHUNK - 1) / SCHUNK;
  int initB = 401 + (N + 63) / 64;   // weight-prep 384 + sums 17 + inproj (64 nodes/block)

  k_pre<<<2, 256, 0, stream>>>(Wl[0], asrcl[0], adstl[0], Win, bin, bcur, vb, c8);

  k_binit<<<BUK + initB, 256, 0, stream>>>(ei, bcur, tmp, E, N,
                                           x, Win, bin, Wl[0], Wl[1], Wl[2],
                                           Wh3, Wcat3, sums, vb, c8, asA, adA, hhA, BUK);

  k_bsort<<<NBUCK, 256, 0, stream>>>(tmp, bcur, rowptr, col, N);

  k_gatf<false><<<tiles, 512, 0, stream>>>(hhA, asA, adA, rowptr, col,
                                           Wcat3, bgl[0], Wh3 + 16384, asrcl[1], adstl[1],
                                           hhB, asB, adB, nullptr, nullptr, N);
  k_gatf<false><<<tiles, 512, 0, stream>>>(hhB, asB, adB, rowptr, col,
                                           Wcat3 + 16384, bgl[1], Wh3 + 32768, asrcl[2], adstl[2],
                                           hhA, asA, adA, nullptr, nullptr, N);
  k_gatf<true><<<tiles, 512, 0, stream>>>(hhA, asA, adA, rowptr, col,
                                          Wcat3 + 32768, bgl[2], nullptr, nullptr, nullptr,
                                          nullptr, nullptr, nullptr, batch, sums, N);

  k_out<<<GCNT, 64, 0, stream>>>(sums, cnt, Wout, bout, (float*)d_out);
}